// Round 6
// baseline (337.129 us; speedup 1.0000x reference)
//
#include <hip/hip_runtime.h>
#include <cstdint>
#include <cstddef>

#define TSEQ   2048
#define BATCH  2
#define BT     4096      // BATCH*TSEQ
#define DMODEL 1024
#define NHEADS 16
#define HDIM   64
#define FFDIM  4096
#define QKVS   3072      // row stride of fused qkv buffer

typedef __attribute__((ext_vector_type(8))) short short8;    // 8 bf16 = 4 VGPRs
typedef __attribute__((ext_vector_type(4))) short short4v;   // 8B of bf16
typedef __attribute__((ext_vector_type(4))) float floatx4;   // MFMA acc
typedef unsigned short us;

__device__ __forceinline__ float bf2f(us u) {
    union { unsigned int i; float f; } v; v.i = ((unsigned int)u) << 16; return v.f;
}
__device__ __forceinline__ us f2bf(float f) {
    union { float f; unsigned int i; } v; v.f = f;
    unsigned int r = v.i + 0x7fffu + ((v.i >> 16) & 1u);
    return (us)(r >> 16);
}
__device__ __forceinline__ unsigned int fbits(float f) {
    union { float f; unsigned int u; } v; v.f = f; return v.u;
}
// pack two f32 -> two bf16 (truncating; P in [0,1] so <=1 ULP down). lo -> low half.
__device__ __forceinline__ unsigned int pk_trunc(float lo, float hi) {
    return (fbits(hi) & 0xffff0000u) | (fbits(lo) >> 16);
}

// async global->LDS, 16B per lane. LDS dest = wave-uniform base + lane*16.
__device__ __forceinline__ void gld_lds16(const us* g, us* l) {
    __builtin_amdgcn_global_load_lds(
        (const __attribute__((address_space(1))) uint32_t*)(const void*)g,
        (__attribute__((address_space(3))) uint32_t*)(void*)l, 16, 0, 0);
}

// ---------------- transpose + cast: in f32 [K][N] -> out bf16 [N][K] ----------------
__global__ void transpose_k(const float* __restrict__ in,
                            us* __restrict__ out, int K, int N) {
    __shared__ us tile[32][33];
    int nt = blockIdx.x * 32, kt = blockIdx.y * 32;
    int tx = threadIdx.x, ty = threadIdx.y; // (32,8)
    for (int i = 0; i < 4; ++i)
        tile[ty + 8 * i][tx] = f2bf(in[(size_t)(kt + ty + 8 * i) * N + nt + tx]);
    __syncthreads();
    for (int i = 0; i < 4; ++i)
        out[(size_t)(nt + ty + 8 * i) * K + kt + tx] = tile[tx][ty + 8 * i];
}

// ---------------- bf16 transpose: V (strided rows) -> Vt [B*D][T], key-permuted ---------
// Within each 64-key block, key k is stored at col sigma(k) = ((k&15)<<2)|((k&63)>>4).
// Matches the packed P storage in attn (storage col c holds key pi(c)=(c&3)*16+(c>>2);
// pi = sigma^-1), so the PV contraction sees identical key order on both operands.
__global__ void vtrans_k(const us* __restrict__ in, us* __restrict__ out, int istride) {
    __shared__ us tile[32][33];
    int b = blockIdx.z;
    int ct = blockIdx.x * 32;   // D tile
    int rt = blockIdx.y * 32;   // T tile
    int tx = threadIdx.x, ty = threadIdx.y; // (32,8)
    for (int i = 0; i < 4; ++i)
        tile[ty + 8 * i][tx] = in[((size_t)b * TSEQ + rt + ty + 8 * i) * istride + ct + tx];
    __syncthreads();
    int tt = rt + tx;
    int ts = (tt & ~63) | ((tt & 15) << 2) | ((tt & 63) >> 4);
    for (int i = 0; i < 4; ++i)
        out[((size_t)b * DMODEL + ct + ty + 8 * i) * TSEQ + ts] = tile[tx][ty + 8 * i];
}

// ---------------- RMSNorm: f32 in -> bf16 out ----------------
__global__ void rmsnorm_k(const float* __restrict__ x,
                          const float* __restrict__ w,
                          us* __restrict__ out) {
    int row = blockIdx.x, t = threadIdx.x;
    float4 xv = *(const float4*)&x[(size_t)row * DMODEL + t * 4];
    float f[4] = {xv.x, xv.y, xv.z, xv.w};
    float ss = 0.f;
    for (int e = 0; e < 4; ++e) ss += f[e] * f[e];
    for (int m = 1; m < 64; m <<= 1) ss += __shfl_xor(ss, m);
    __shared__ float red[4];
    if ((t & 63) == 0) red[t >> 6] = ss;
    __syncthreads();
    float tot = red[0] + red[1] + red[2] + red[3];
    float sc = rsqrtf(tot * (1.f / DMODEL) + 1e-6f);
    float4 wv = *(const float4*)&w[t * 4];
    float wf[4] = {wv.x, wv.y, wv.z, wv.w};
    us ol[4];
    for (int e = 0; e < 4; ++e) ol[e] = f2bf(f[e] * sc * wf[e]);
    *(uint2*)&out[(size_t)row * DMODEL + t * 4] = *(uint2*)ol;
}

// ---------------- Residual + RMSNorm: out = rmsnorm(a + b [+ b2]) * w ----------------
// NOTE: out may alias a (row-local, each thread rewrites exactly what it read) -> no __restrict__.
__global__ void resnorm_k(const us* a, const us* b,
                          const us* b2,
                          const float* w,
                          void* outp, int out_f32) {
    int row = blockIdx.x, t = threadIdx.x;
    us al[4], bl[4], cl[4];
    *(uint2*)al = *(const uint2*)&a[(size_t)row * DMODEL + t * 4];
    *(uint2*)bl = *(const uint2*)&b[(size_t)row * DMODEL + t * 4];
    if (b2) *(uint2*)cl = *(const uint2*)&b2[(size_t)row * DMODEL + t * 4];
    float f[4];
    float ss = 0.f;
    for (int e = 0; e < 4; ++e) {
        f[e] = bf2f(al[e]) + bf2f(bl[e]);
        if (b2) f[e] += bf2f(cl[e]);
        ss += f[e] * f[e];
    }
    for (int m = 1; m < 64; m <<= 1) ss += __shfl_xor(ss, m);
    __shared__ float red[4];
    if ((t & 63) == 0) red[t >> 6] = ss;
    __syncthreads();
    float tot = red[0] + red[1] + red[2] + red[3];
    float sc = rsqrtf(tot * (1.f / DMODEL) + 1e-6f);
    float4 wv = *(const float4*)&w[t * 4];
    float wf[4] = {wv.x, wv.y, wv.z, wv.w};
    if (out_f32) {
        float4 ov;
        ov.x = f[0] * sc * wf[0]; ov.y = f[1] * sc * wf[1];
        ov.z = f[2] * sc * wf[2]; ov.w = f[3] * sc * wf[3];
        *(float4*)&((float*)outp)[(size_t)row * DMODEL + t * 4] = ov;
    } else {
        us ol[4];
        for (int e = 0; e < 4; ++e) ol[e] = f2bf(f[e] * sc * wf[e]);
        *(uint2*)&((us*)outp)[(size_t)row * DMODEL + t * 4] = *(uint2*)ol;
    }
}

// ---------------- Residual + RMSNorm over 4 split-K partials (f32 out) ----------------
__global__ void resnorm4_k(const us* __restrict__ a, const us* __restrict__ p,
                           size_t pstride, const float* __restrict__ w,
                           float* __restrict__ out) {
    int row = blockIdx.x, t = threadIdx.x;
    size_t off = (size_t)row * DMODEL + t * 4;
    us al[4], pl[4][4];
    *(uint2*)al = *(const uint2*)&a[off];
#pragma unroll
    for (int z = 0; z < 4; ++z)
        *(uint2*)pl[z] = *(const uint2*)&p[off + z * pstride];
    float f[4];
    float ss = 0.f;
#pragma unroll
    for (int e = 0; e < 4; ++e) {
        f[e] = bf2f(al[e]) + bf2f(pl[0][e]) + bf2f(pl[1][e]) + bf2f(pl[2][e]) + bf2f(pl[3][e]);
        ss += f[e] * f[e];
    }
    for (int m = 1; m < 64; m <<= 1) ss += __shfl_xor(ss, m);
    __shared__ float red[4];
    if ((t & 63) == 0) red[t >> 6] = ss;
    __syncthreads();
    float tot = red[0] + red[1] + red[2] + red[3];
    float sc = rsqrtf(tot * (1.f / DMODEL) + 1e-6f);
    float4 wv = *(const float4*)&w[t * 4];
    float4 ov;
    ov.x = f[0] * sc * wv.x; ov.y = f[1] * sc * wv.y;
    ov.z = f[2] * sc * wv.z; ov.w = f[3] * sc * wv.w;
    *(float4*)&out[off] = ov;
}

// ---------------- legacy 128-tile 2-phase GEMM (kept for O-proj: short K, small) -------
template<int BN, int GX, bool SWZ>
__global__ __launch_bounds__(256, (BN == 256) ? 2 : 4)
void gemm_dbuf_k(const us* __restrict__ A,
                 const us* __restrict__ Bt,
                 us* __restrict__ C,
                 int M, int N, int K, int do_silu,
                 int Ks, size_t cstride) {
    constexpr int MI = 4, NI = BN / 32;
    constexpr int BDMA = BN / 64;
    __shared__ __align__(16) us As[2][128 * 32];
    __shared__ __align__(16) us Bs[2][BN * 32];
    int t = threadIdx.x;
    int n0 = blockIdx.x;
    int bx, by, z;
    if (SWZ) {
        int c = n0 & 7, bb = n0 >> 3;
        bx = bb % GX;
        int g = bb / GX;
        int yz = c + 8 * g;
        by = yz & 31; z = yz >> 5;
    } else {
        bx = n0 % GX;
        int bb = n0 / GX;
        by = bb & 31; z = bb >> 5;
    }
    int bm = by * 128, bn = bx * BN;
    int lane = t & 63, wave = t >> 6;
    int wm = (wave & 1) * 64, wn = (wave >> 1) * (BN / 2);
    int lr = lane & 15, lq = lane >> 4;

    int sr = lane >> 2;
    int sc = (((lane & 3) ^ ((lane >> 3) & 3)) * 8);
    const us* gA = A + (size_t)(bm + wave * 32 + sr) * K + sc + (size_t)z * Ks;
    const us* gB = Bt + (size_t)(bn + wave * (BN / 4) + sr) * K + sc + (size_t)z * Ks;
    const int aoff = (wave * 32) * 32;
    const int boff = (wave * (BN / 4)) * 32;
    C += (size_t)z * cstride;

    floatx4 acc[MI][NI];
#pragma unroll
    for (int mi = 0; mi < MI; ++mi)
#pragma unroll
        for (int ni = 0; ni < NI; ++ni)
            acc[mi][ni] = (floatx4){0.f, 0.f, 0.f, 0.f};

#pragma unroll
    for (int i = 0; i < 2; ++i)
        gld_lds16(gA + (size_t)(16 * i) * K, &As[0][aoff + i * 16 * 32]);
#pragma unroll
    for (int i = 0; i < BDMA; ++i)
        gld_lds16(gB + (size_t)(16 * i) * K, &Bs[0][boff + i * 16 * 32]);

    int aslot = ((lq ^ ((lr >> 1) & 3)) << 3);

    int nk = Ks >> 5;
    for (int kk = 0; kk < nk; ++kk) {
        __syncthreads();
        int cur = kk & 1, nxt = cur ^ 1;
        if (kk + 1 < nk) {
            size_t off = (size_t)(kk + 1) * 32;
#pragma unroll
            for (int i = 0; i < 2; ++i)
                gld_lds16(gA + (size_t)(16 * i) * K + off, &As[nxt][aoff + i * 16 * 32]);
#pragma unroll
            for (int i = 0; i < BDMA; ++i)
                gld_lds16(gB + (size_t)(16 * i) * K + off, &Bs[nxt][boff + i * 16 * 32]);
        }
        short8 a[MI], b[NI];
#pragma unroll
        for (int mi = 0; mi < MI; ++mi)
            a[mi] = *(const short8*)&As[cur][(wm + mi * 16 + lr) * 32 + aslot];
#pragma unroll
        for (int ni = 0; ni < NI; ++ni)
            b[ni] = *(const short8*)&Bs[cur][(wn + ni * 16 + lr) * 32 + aslot];
#pragma unroll
        for (int mi = 0; mi < MI; ++mi)
#pragma unroll
            for (int ni = 0; ni < NI; ++ni)
                acc[mi][ni] = __builtin_amdgcn_mfma_f32_16x16x32_bf16(a[mi], b[ni], acc[mi][ni], 0, 0, 0);
    }

#pragma unroll
    for (int mi = 0; mi < MI; ++mi)
#pragma unroll
        for (int ni = 0; ni < NI; ++ni)
#pragma unroll
            for (int r = 0; r < 4; ++r) {
                int m = bm + wm + mi * 16 + lq * 4 + r;
                int nn = bn + wn + ni * 16 + lr;
                float v = acc[mi][ni][r];
                if (do_silu) v = v / (1.f + __expf(-v));
                C[(size_t)m * N + nn] = f2bf(v);
            }
}

// ================= R18: 256x256 4-phase GEMM (merged from the 8-phase template) ==========
// Evidence: R17's 8-phase QKV/FFN1/FFN2 all pinned at 49.4us regardless of FLOPs/fetch ->
// fixed per-phase-event cost dominates. Halve events: 4 phases per K-pair, 32 MFMA each.
// Stage map (re-derived race-free; stages land in regions whose last read was a full
// phase earlier, or in the opposite operand array from this phase's reads):
//   Q1: reads T0.B(all)+T0.A(mf0-3); stages T1.A(h0+h1)  [buf1.A idle]
//   Q2: reads T0.A(mf4-7);           stages T2.B(h0+h1)  [buf0.B read done Q1] + VM4
//   Q3: reads T1.B(all)+T1.A(mf0-3); stages T2.A(h0+h1)  [buf0.A read done Q2]
//   Q4: reads T1.A(mf4-7);           stages T3.B(h0+h1)  [buf1.B read done Q3] + VM4
// vmcnt invariant: 4 outstanding (next tile's B) at iteration entry; VM4 at Q2 proves T1
// landed before Q3 reads it; VM4 at Q4 proves T2 before next Q1.

#define BAR8 __builtin_amdgcn_s_barrier()
#define WLGKM do { asm volatile("s_waitcnt lgkmcnt(0)" ::: "memory"); \
                   __builtin_amdgcn_sched_barrier(0); } while (0)
#define VM4 do { asm volatile("s_waitcnt vmcnt(4)" ::: "memory"); } while (0)
#define VM0 do { asm volatile("s_waitcnt vmcnt(0)" ::: "memory"); } while (0)

template<int GX>
__global__ __launch_bounds__(512, 2)
void gemm8p_k(const us* __restrict__ A, const us* __restrict__ Bt, us* __restrict__ C,
              int N, int K, int Ks, int do_silu, size_t cstride) {
    __shared__ __align__(16) us Alds[2 * 2 * 128 * 64];   // 64 KiB
    __shared__ __align__(16) us Blds[2 * 2 * 128 * 64];   // 64 KiB
    int t = threadIdx.x, lane = t & 63, wave = t >> 6;
    int n0 = blockIdx.x;
    int by = n0 & 15, rest = n0 >> 4;       // M=4096 fixed -> 16 row-blocks
    int bx = rest % GX, z = rest / GX;
    int bm = by * 256, bn = bx * 256;
    int lr = lane & 15, lq = (lane >> 4) & 3;
    int wm2 = wave >> 2, wn2 = wave & 3;

    // staging source (pre-swizzled chunk: LDS[row][c] = G[row][c ^ (row&7)])
    const us* gA = A + (size_t)(bm + wave * 16 + (lane >> 3)) * K
                     + ((lane & 7) ^ (lane >> 3)) * 8 + (size_t)z * Ks;
    const us* gB = Bt + (size_t)(bn + wave * 16 + (lane >> 3)) * K
                      + ((lane & 7) ^ (lane >> 3)) * 8 + (size_t)z * Ks;
    const int sd = wave * 1024;             // wave's 16 rows x 64 within a half
    C += (size_t)z * cstride;

    // ds_read swizzled slots for Ksub 0/1: slot = chunk ^ (row&7), row&7 == lr&7
    const int sw0 = ((lq ^ (lr & 7)) * 8);
    const int sw1 = (((4 + lq) ^ (lr & 7)) * 8);
    const int aoffs = wm2 * 8192 + lr * 64;                            // wave's A half
    const int boffs = (wn2 >> 1) * 8192 + (wn2 & 1) * 4096 + lr * 64;  // wave's B cols

#define STG_A(d, h, tt) do { \
    gld_lds16(gA + (size_t)((h) * 128) * K + (size_t)(tt) * 64, \
              &Alds[(d) * 16384 + (h) * 8192 + sd]); \
    gld_lds16(gA + (size_t)((h) * 128 + 8) * K + (size_t)(tt) * 64, \
              &Alds[(d) * 16384 + (h) * 8192 + sd + 512]); } while (0)
#define STG_B(d, h, tt) do { \
    gld_lds16(gB + (size_t)((h) * 128) * K + (size_t)(tt) * 64, \
              &Blds[(d) * 16384 + (h) * 8192 + sd]); \
    gld_lds16(gB + (size_t)((h) * 128 + 8) * K + (size_t)(tt) * 64, \
              &Blds[(d) * 16384 + (h) * 8192 + sd + 512]); } while (0)
#define STG_A2(d, tt) do { STG_A(d, 0, tt); STG_A(d, 1, tt); } while (0)
#define STG_B2(d, tt) do { STG_B(d, 0, tt); STG_B(d, 1, tt); } while (0)
#define RDA(sl, mf, dd) do { \
    aF[sl][0] = *(const short8*)&Alds[(dd) * 16384 + aoffs + (mf) * 1024 + sw0]; \
    aF[sl][1] = *(const short8*)&Alds[(dd) * 16384 + aoffs + (mf) * 1024 + sw1]; } while (0)
#define RDB(nf, dd) do { \
    bF[nf][0] = *(const short8*)&Blds[(dd) * 16384 + boffs + (nf) * 1024 + sw0]; \
    bF[nf][1] = *(const short8*)&Blds[(dd) * 16384 + boffs + (nf) * 1024 + sw1]; } while (0)
#define MMROW(mf, sl) do { \
    acc[mf][0] = __builtin_amdgcn_mfma_f32_16x16x32_bf16(aF[sl][0], bF[0][0], acc[mf][0], 0, 0, 0); \
    acc[mf][1] = __builtin_amdgcn_mfma_f32_16x16x32_bf16(aF[sl][0], bF[1][0], acc[mf][1], 0, 0, 0); \
    acc[mf][2] = __builtin_amdgcn_mfma_f32_16x16x32_bf16(aF[sl][0], bF[2][0], acc[mf][2], 0, 0, 0); \
    acc[mf][3] = __builtin_amdgcn_mfma_f32_16x16x32_bf16(aF[sl][0], bF[3][0], acc[mf][3], 0, 0, 0); \
    acc[mf][0] = __builtin_amdgcn_mfma_f32_16x16x32_bf16(aF[sl][1], bF[0][1], acc[mf][0], 0, 0, 0); \
    acc[mf][1] = __builtin_amdgcn_mfma_f32_16x16x32_bf16(aF[sl][1], bF[1][1], acc[mf][1], 0, 0, 0); \
    acc[mf][2] = __builtin_amdgcn_mfma_f32_16x16x32_bf16(aF[sl][1], bF[2][1], acc[mf][2], 0, 0, 0); \
    acc[mf][3] = __builtin_amdgcn_mfma_f32_16x16x32_bf16(aF[sl][1], bF[3][1], acc[mf][3], 0, 0, 0); } while (0)
#define PRIO1 __builtin_amdgcn_s_setprio(1)
#define PRIO0 __builtin_amdgcn_s_setprio(0)

    floatx4 acc[8][4];
#pragma unroll
    for (int mf = 0; mf < 8; ++mf)
#pragma unroll
        for (int nf = 0; nf < 4; ++nf)
            acc[mf][nf] = (floatx4){0.f, 0.f, 0.f, 0.f};

    short8 aF[4][2], bF[4][2];

    // prologue: tile0 complete + tile1 B halves (T1.A staged at Q1). 12 loads; VM4 ->
    // oldest 8 (= all of tile0) landed; 4 outstanding (T1.B) = loop invariant.
    STG_B2(0, 0); STG_A2(0, 0); STG_B2(1, 1);
    VM4; BAR8;

    const int NK2 = Ks >> 7;               // (Ks/64)/2 pairs; Ks=1024 -> 8
    for (int i = 0; i < NK2 - 1; ++i) {
        int t1 = 2 * i + 1, t2 = 2 * i + 2, t3 = 2 * i + 3;
        // Q1 (tile 2i, buf0): B all + A mf0-3; stage T1.A -> buf1.A (idle)
        RDB(0, 0); RDB(1, 0); RDB(2, 0); RDB(3, 0);
        RDA(0, 0, 0); RDA(1, 1, 0); RDA(2, 2, 0); RDA(3, 3, 0);
        STG_A2(1, t1);
        BAR8; WLGKM; PRIO1; MMROW(0, 0); MMROW(1, 1); MMROW(2, 2); MMROW(3, 3); PRIO0; BAR8;
        // Q2: A mf4-7; stage T2.B -> buf0.B (read done in Q1); VM4 proves T1 landed
        RDA(0, 4, 0); RDA(1, 5, 0); RDA(2, 6, 0); RDA(3, 7, 0);
        STG_B2(0, t2);
        VM4; BAR8; WLGKM; PRIO1; MMROW(4, 0); MMROW(5, 1); MMROW(6, 2); MMROW(7, 3); PRIO0; BAR8;
        // Q3 (tile 2i+1, buf1): B all + A mf0-3; stage T2.A -> buf0.A (read done in Q2)
        RDB(0, 1); RDB(1, 1); RDB(2, 1); RDB(3, 1);
        RDA(0, 0, 1); RDA(1, 1, 1); RDA(2, 2, 1); RDA(3, 3, 1);
        STG_A2(0, t2);
        BAR8; WLGKM; PRIO1; MMROW(0, 0); MMROW(1, 1); MMROW(2, 2); MMROW(3, 3); PRIO0; BAR8;
        // Q4: A mf4-7; stage T3.B -> buf1.B (read done in Q3); VM4 proves T2 landed
        RDA(0, 4, 1); RDA(1, 5, 1); RDA(2, 6, 1); RDA(3, 7, 1);
        STG_B2(1, t3);
        VM4; BAR8; WLGKM; PRIO1; MMROW(4, 0); MMROW(5, 1); MMROW(6, 2); MMROW(7, 3); PRIO0; BAR8;
    }
    {   // peeled last pair: only T1.A still needs staging (Q1); drain fully at Q2
        int t1 = 2 * NK2 - 1;
        RDB(0, 0); RDB(1, 0); RDB(2, 0); RDB(3, 0);
        RDA(0, 0, 0); RDA(1, 1, 0); RDA(2, 2, 0); RDA(3, 3, 0);
        STG_A2(1, t1);
        BAR8; WLGKM; PRIO1; MMROW(0, 0); MMROW(1, 1); MMROW(2, 2); MMROW(3, 3); PRIO0; BAR8;
        RDA(0, 4, 0); RDA(1, 5, 0); RDA(2, 6, 0); RDA(3, 7, 0);
        VM0; BAR8; WLGKM; PRIO1; MMROW(4, 0); MMROW(5, 1); MMROW(6, 2); MMROW(7, 3); PRIO0; BAR8;
        // last tile (buf1), fully staged
        RDB(0, 1); RDB(1, 1); RDB(2, 1); RDB(3, 1);
        RDA(0, 0, 1); RDA(1, 1, 1); RDA(2, 2, 1); RDA(3, 3, 1);
        BAR8; WLGKM; PRIO1; MMROW(0, 0); MMROW(1, 1); MMROW(2, 2); MMROW(3, 3); PRIO0; BAR8;
        RDA(0, 4, 1); RDA(1, 5, 1); RDA(2, 6, 1); RDA(3, 7, 1);
        WLGKM; PRIO1; MMROW(4, 0); MMROW(5, 1); MMROW(6, 2); MMROW(7, 3); PRIO0;
    }

    // epilogue: C/D layout col = lane&15, row = (lane>>4)*4 + r
    int cm = bm + wm2 * 128, cn = bn + wn2 * 64;
#pragma unroll
    for (int mf = 0; mf < 8; ++mf)
#pragma unroll
        for (int nf = 0; nf < 4; ++nf)
#pragma unroll
            for (int r = 0; r < 4; ++r) {
                int m = cm + mf * 16 + lq * 4 + r;
                int nn = cn + nf * 16 + lr;
                float v = acc[mf][nf][r];
                if (do_silu) v = v / (1.f + __expf(-v));
                C[(size_t)m * N + nn] = f2bf(v);
            }
#undef STG_A
#undef STG_B
#undef STG_A2
#undef STG_B2
#undef RDA
#undef RDB
#undef MMROW
#undef PRIO1
#undef PRIO0
}

// ================= Flash attention: 512-thread blocks, 2 q-tiles sharing one K/V pass ======
// R17: P materialized via truncating bit-pack + ds_write_b64 (short4v, same TBAA class as
// the short8 reload) + explicit lgkmcnt(0)+sched_barrier fence before the PV reads.
// P storage col c holds key pi(c)=(c&3)*16+(c>>2); V is pre-permuted by sigma=pi^-1
// in vtrans_k so PV k-slots line up.
#define PSTR 72

template<bool DIAG>
__device__ __forceinline__ void flash_tile_nm(
    const short8& qf0, const short8& qf1,
    floatx4* oa, float* lrw,
    const us* Ks, const us* Vts, us* Ps, const short8& ones,
    int lr, int lq, int sub)
{
    floatx4 s[4];
#pragma unroll
    for (int n = 0; n < 4; ++n) {
        int R = n * 16 + lr;
        short8 kf0 = *(const short8*)&Ks[R * 64 + ((lq ^ (R & 7)) << 3)];
        short8 kf1 = *(const short8*)&Ks[R * 64 + (((lq + 4) ^ (R & 7)) << 3)];
        floatx4 z = (floatx4){0.f, 0.f, 0.f, 0.f};
        z = __builtin_amdgcn_mfma_f32_16x16x32_bf16(qf0, kf0, z, 0, 0, 0);
        s[n] = __builtin_amdgcn_mfma_f32_16x16x32_bf16(qf1, kf1, z, 0, 0, 0);
    }
    if (DIAG) {
#pragma unroll
        for (int n = 0; n < 4; ++n)
#pragma unroll
            for (int r = 0; r < 4; ++r)
                if ((n * 16 + lr) > (sub * 16 + lq * 4 + r)) s[n][r] = -1e30f;  // exp2 -> 0
    }
    // packed P write: keys {n*16+lr} -> storage cols lr*4+n (pi-permuted layout)
#pragma unroll
    for (int r = 0; r < 4; ++r) {
        union { unsigned int u[2]; short4v v; } pk;
        pk.u[0] = pk_trunc(__builtin_amdgcn_exp2f(s[0][r]), __builtin_amdgcn_exp2f(s[1][r]));
        pk.u[1] = pk_trunc(__builtin_amdgcn_exp2f(s[2][r]), __builtin_amdgcn_exp2f(s[3][r]));
        *(short4v*)&Ps[(lq * 4 + r) * PSTR + lr * 4] = pk.v;
    }
    // ensure the 4 ds_write_b64 above complete before the same wave's ds_reads below
    asm volatile("s_waitcnt lgkmcnt(0)" ::: "memory");
    __builtin_amdgcn_sched_barrier(0);

    floatx4 zs = (floatx4){0.f, 0.f, 0.f, 0.f};
    __builtin_amdgcn_s_setprio(1);
#pragma unroll
    for (int kx = 0; kx < 2; ++kx) {
        short8 pf = *(const short8*)&Ps[lr * PSTR + kx * 32 + lq * 8];
        zs = __builtin_amdgcn_mfma_f32_16x16x32_bf16(pf, ones, zs, 0, 0, 0);
#pragma unroll
        for (int nd = 0; nd < 4; ++nd) {
            int R = nd * 16 + lr;
            short8 vf = *(const short8*)&Vts[R * 64 + ((((kx << 2) | lq) ^ (R & 7)) << 3)];
            oa[nd] = __builtin_amdgcn_mfma_f32_16x16x32_bf16(pf, vf, oa[nd], 0, 0, 0);
        }
    }
    __builtin_amdgcn_s_setprio(0);
#pragma unroll
    for (int r = 0; r < 4; ++r) lrw[r] += zs[r];
}

__global__ __launch_bounds__(512, 6) void attn_k(const us* __restrict__ q,
                                                 const us* __restrict__ kg,
                                                 const us* __restrict__ vt,
                                                 us* __restrict__ o,
                                                 us* __restrict__ Po,
                                                 float* __restrict__ Pl) {
    __shared__ __align__(16) us Ks[2][64 * 64];
    __shared__ __align__(16) us Vts[2][64 * 64];
    __shared__ __align__(16) us Ps[8 * 16 * PSTR];
    int j = blockIdx.x;
    int part = (j >= 16);
    int P = part ? (j - 8) : j;
    int qtA = 2 * P, qtB = 2 * P + 1;
    int k0 = part ? 16 : 0;
    int k1 = part ? qtB : (qtB < 15 ? qtB : 15);
    bool fin = (!part) && (P < 8);
    int bh = blockIdx.y;
    int b = bh >> 4, h = bh & 15;
    size_t base = (size_t)b * TSEQ;
    const us* vth = vt + ((size_t)b * DMODEL + h * 64) * TSEQ;
    int t = threadIdx.x, lane = t & 63, wave = t >> 6;   // wave 0..7
    int sub = wave & 3, grp = wave >> 2;                 // strip index, q-tile group
    int myqt = grp ? qtB : qtA;
    int lr = lane & 15, lq = lane >> 4;

    const float SC = 0.18033688011112042f;  // (1/8)*log2(e)
    int qrow = myqt * 64 + sub * 16 + lr;
    short8 qf0 = *(const short8*)&q[(base + qrow) * QKVS + h * 64 + lq * 8];
    short8 qf1 = *(const short8*)&q[(base + qrow) * QKVS + h * 64 + 32 + lq * 8];
#pragma unroll
    for (int e = 0; e < 8; ++e) {
        qf0[e] = (short)f2bf(bf2f((us)qf0[e]) * SC);
        qf1[e] = (short)f2bf(bf2f((us)qf1[e]) * SC);
    }
    short8 ones;
#pragma unroll
    for (int e = 0; e < 8; ++e) ones[e] = (short)0x3F80;  // bf16 1.0

    us* Psw = &Ps[wave * 16 * PSTR];

    floatx4 oa[4];
    float lrw[4] = {0.f, 0.f, 0.f, 0.f};
#pragma unroll
    for (int i = 0; i < 4; ++i) oa[i] = (floatx4){0.f, 0.f, 0.f, 0.f};

    int rsub = lane >> 3;
    int cda = ((lane & 7) ^ rsub) * 8;
    const us* gK = kg + (base + wave * 8 + rsub) * QKVS + h * 64 + cda;
    const us* gV = vth + (size_t)(wave * 8 + rsub) * TSEQ + cda;

    gld_lds16(gK + (size_t)(k0 * 64) * QKVS, &Ks[0][(wave * 8) * 64]);
    gld_lds16(gV + k0 * 64, &Vts[0][(wave * 8) * 64]);

    for (int kt = k0; kt <= k1; ++kt) {
        __syncthreads();
        int cur = (kt - k0) & 1, nxt = cur ^ 1;
        if (kt < k1) {
            gld_lds16(gK + (size_t)((kt + 1) * 64) * QKVS, &Ks[nxt][(wave * 8) * 64]);
            gld_lds16(gV + (kt + 1) * 64, &Vts[nxt][(wave * 8) * 64]);
        }
        if (kt <= myqt) {
            if (kt == myqt)
                flash_tile_nm<true>(qf0, qf1, oa, lrw, Ks[cur], Vts[cur], Psw, ones, lr, lq, sub);
            else
                flash_tile_nm<false>(qf0, qf1, oa, lrw, Ks[cur], Vts[cur], Psw, ones, lr, lq, sub);
        }
    }

    if (fin) {
#pragma unroll
        for (int nd = 0; nd < 4; ++nd)
#pragma unroll
            for (int r = 0; r < 4; ++r) {
                int tok = myqt * 64 + sub * 16 + lq * 4 + r;
                o[(base + tok) * DMODEL + h * 64 + nd * 16 + lr] = f2bf(oa[nd][r] / lrw[r]);
            }
    } else {
#pragma unroll
        for (int nd = 0; nd < 4; ++nd)
#pragma unroll
            for (int r = 0; r < 4; ++r) {
                int tok = myqt * 64 + sub * 16 + lq * 4 + r;
                size_t pb = ((size_t)(part * BATCH + b) * 1024 + (tok - 1024)) * 1024;
                Po[pb + h * 64 + nd * 16 + lr] = f2bf(oa[nd][r]);
            }
        if (lr == 0) {
#pragma unroll
            for (int r = 0; r < 4; ++r) {
                int tok = myqt * 64 + sub * 16 + lq * 4 + r;
                Pl[((part * BATCH + b) * NHEADS + h) * TSEQ + tok] = lrw[r];
            }
        }
    }
}

__global__ void merge_k(const us* __restrict__ Po, const float* __restrict__ Pl,
                        us* __restrict__ ab) {
    int row = blockIdx.x;            // 0..2047
    int b = row >> 10, tloc = row & 1023;
    int t = 1024 + tloc;
    int t4 = threadIdx.x * 4;
    int h = t4 >> 6;
    float l0 = Pl[((0 * BATCH + b) * NHEADS + h) * TSEQ + t];
    float l1 = Pl[((1 * BATCH + b) * NHEADS + h) * TSEQ + t];
    float inv = 1.f / (l0 + l1);
    size_t o0 = ((size_t)(0 * BATCH + b) * 1024 + tloc) * 1024 + t4;
    size_t o1 = ((size_t)(1 * BATCH + b) * 1024 + tloc) * 1024 + t4;
    us p0[4], p1[4], ol[4];
    *(uint2*)p0 = *(const uint2*)&Po[o0];
    *(uint2*)p1 = *(const uint2*)&Po[o1];
    for (int e = 0; e < 4; ++e)
        ol[e] = f2bf((bf2f(p0[e]) + bf2f(p1[e])) * inv);
    *(uint2*)&ab[((size_t)b * TSEQ + t) * DMODEL + t4] = *(uint2*)ol;
}

// ---------------- launch ----------------
extern "C" void kernel_launch(void* const* d_in, const int* in_sizes, int n_in,
                              void* d_out, int out_size, void* d_ws, size_t ws_size,
                              hipStream_t stream) {
    const float* x      = (const float*)d_in[0];
    const float* w_pre  = (const float*)d_in[1];
    const float* wq     = (const float*)d_in[2];
    const float* wk     = (const float*)d_in[3];
    const float* wv     = (const float*)d_in[4];
    const float* wo     = (const float*)d_in[5];
    const float* w_attn = (const float*)d_in[6];
    const float* w1     = (const float*)d_in[7];
    const float* w2     = (const float*)d_in[8];
    const float* w_ffn  = (const float*)d_in[9];

    char* ws = (char*)d_ws;
    const size_t MB = 1024 * 1024;
    us* hb    = (us*)(ws + 0);
    us* qkvb  = (us*)(ws + 8 * MB);
    us* ab    = (us*)(ws + 32 * MB);
    us* vtb   = (us*)(ws + 40 * MB);
    us* ob0   = (us*)(ws + 40 * MB);
    us* ob1   = (us*)(ws + 48 * MB);
    us* Pob   = (us*)(ws + 48 * MB);
    us* yb    = (us*)(ws + 0);        // in-place over hb (row-local safe)
    us* wqkvt = (us*)(ws + 56 * MB);  // 6 MB
    us* wot   = (us*)(ws + 62 * MB);  // 2 MB
    us* w1t   = (us*)(ws + 64 * MB);  // 8 MB
    us* w2t   = (us*)(ws + 72 * MB);  // 8 MB
    float* Pl = (float*)(ws + 80 * MB); // 1 MB
    us* midb  = (us*)(ws + 8 * MB);   // 32 MB FFN mid (qkvb+ab dead)
    us* fb0   = (us*)(ws + 40 * MB);  // FFN2 split-K=4 partials, 8 MB stride
    const size_t FB_STR = (8 * MB) / 2;

    dim3 tb(32, 8);
    transpose_k<<<dim3(32, 32), tb, 0, stream>>>(wq, wqkvt, DMODEL, DMODEL);
    transpose_k<<<dim3(32, 32), tb, 0, stream>>>(wk, wqkvt + 1024 * 1024, DMODEL, DMODEL);
    transpose_k<<<dim3(32, 32), tb, 0, stream>>>(wv, wqkvt + 2 * 1024 * 1024, DMODEL, DMODEL);
    transpose_k<<<dim3(32, 32), tb, 0, stream>>>(wo, wot, DMODEL, DMODEL);
    transpose_k<<<dim3(FFDIM / 32, 32), tb, 0, stream>>>(w1, w1t, DMODEL, FFDIM);
    transpose_k<<<dim3(32, FFDIM / 32), tb, 0, stream>>>(w2, w2t, FFDIM, DMODEL);

    rmsnorm_k<<<BT, 256, 0, stream>>>(x, w_pre, hb);

    // fused QKV: 4-phase 256x256, 16x12 = 192 blocks
    gemm8p_k<12><<<dim3(192), 512, 0, stream>>>(
        hb, wqkvt, qkvb, QKVS, DMODEL, DMODEL, 0, 0);

    vtrans_k<<<dim3(DMODEL / 32, TSEQ / 32, BATCH), tb, 0, stream>>>(qkvb + 2048, vtb, QKVS);

    attn_k<<<dim3(24, BATCH * NHEADS), 512, 0, stream>>>(qkvb, qkvb + 1024, vtb, ab, Pob, Pl);
    merge_k<<<dim3(BATCH * 1024), 256, 0, stream>>>(Pob, Pl, ab);

    // O-proj: legacy 2-phase, GX=8, split-K=2 -> 512 blocks (short K; small op)
    gemm_dbuf_k<128, 8, true><<<dim3(512), 256, 0, stream>>>(
        ab, wot, ob0, BT, DMODEL, DMODEL, 0, DMODEL / 2, (size_t)BT * DMODEL);
    resnorm_k<<<BT, 256, 0, stream>>>(hb, ob0, ob1, w_attn, yb, 0);

    // FFN1: 4-phase 256x256, 16x16 = 256 blocks, fused silu
    gemm8p_k<16><<<dim3(256), 512, 0, stream>>>(
        yb, w1t, midb, FFDIM, DMODEL, DMODEL, 1, 0);
    // FFN2: 4-phase 256x256, split-K=4 -> 16x4x4 = 256 blocks, Ks=1024
    gemm8p_k<4><<<dim3(256), 512, 0, stream>>>(
        midb, w2t, fb0, DMODEL, FFDIM, FFDIM / 4, 0, FB_STR);
    resnorm4_k<<<BT, 256, 0, stream>>>(yb, fb0, FB_STR, w_ffn, (float*)d_out);
}

// Round 7
// 316.721 us; speedup vs baseline: 1.0644x; 1.0644x over previous
//
#include <hip/hip_runtime.h>
#include <cstdint>
#include <cstddef>

#define TSEQ   2048
#define BATCH  2
#define BT     4096      // BATCH*TSEQ
#define DMODEL 1024
#define NHEADS 16
#define HDIM   64
#define FFDIM  4096
#define QKVS   3072      // row stride of fused qkv buffer

typedef __attribute__((ext_vector_type(8))) short short8;    // 8 bf16 = 4 VGPRs
typedef __attribute__((ext_vector_type(4))) short short4v;   // 8B of bf16
typedef __attribute__((ext_vector_type(4))) float floatx4;   // MFMA acc
typedef unsigned short us;

__device__ __forceinline__ float bf2f(us u) {
    union { unsigned int i; float f; } v; v.i = ((unsigned int)u) << 16; return v.f;
}
__device__ __forceinline__ us f2bf(float f) {
    union { float f; unsigned int i; } v; v.f = f;
    unsigned int r = v.i + 0x7fffu + ((v.i >> 16) & 1u);
    return (us)(r >> 16);
}
__device__ __forceinline__ unsigned int fbits(float f) {
    union { float f; unsigned int u; } v; v.f = f; return v.u;
}
// pack two f32 -> two bf16 (truncating; P in [0,1] so <=1 ULP down). lo -> low half.
__device__ __forceinline__ unsigned int pk_trunc(float lo, float hi) {
    return (fbits(hi) & 0xffff0000u) | (fbits(lo) >> 16);
}

// async global->LDS, 16B per lane. LDS dest = wave-uniform base + lane*16.
__device__ __forceinline__ void gld_lds16(const us* g, us* l) {
    __builtin_amdgcn_global_load_lds(
        (const __attribute__((address_space(1))) uint32_t*)(const void*)g,
        (__attribute__((address_space(3))) uint32_t*)(void*)l, 16, 0, 0);
}

// ============ R19 prologue: 6 weight transposes + pre-norm fused into one launch =========
// blocks [0,12288): 32x32 transpose tiles (wq,wk,wv,wo: 4x1024 | w1: 4096 | w2: 4096)
// blocks [12288,16384): rmsnorm rows. All branches are block-uniform.
__global__ void prologue_k(const float* __restrict__ wq, const float* __restrict__ wk,
                           const float* __restrict__ wv, const float* __restrict__ wo,
                           const float* __restrict__ w1, const float* __restrict__ w2,
                           const float* __restrict__ x,  const float* __restrict__ w_pre,
                           us* __restrict__ wqkvt, us* __restrict__ wot,
                           us* __restrict__ w1t, us* __restrict__ w2t,
                           us* __restrict__ hb) {
    __shared__ us tile[32][33];
    __shared__ float red[4];
    int tb = blockIdx.x;
    int tx = threadIdx.x, ty = threadIdx.y;  // (32,8)
    if (tb >= 12288) {                        // ---- rmsnorm row ----
        int row = tb - 12288;
        int tid = ty * 32 + tx;
        float4 xv = *(const float4*)&x[(size_t)row * DMODEL + tid * 4];
        float f[4] = {xv.x, xv.y, xv.z, xv.w};
        float ss = 0.f;
        for (int e = 0; e < 4; ++e) ss += f[e] * f[e];
        for (int m = 1; m < 64; m <<= 1) ss += __shfl_xor(ss, m);
        if ((tid & 63) == 0) red[tid >> 6] = ss;
        __syncthreads();
        float tot = red[0] + red[1] + red[2] + red[3];
        float sc = rsqrtf(tot * (1.f / DMODEL) + 1e-6f);
        float4 wv4 = *(const float4*)&w_pre[tid * 4];
        float wf[4] = {wv4.x, wv4.y, wv4.z, wv4.w};
        us ol[4];
        for (int e = 0; e < 4; ++e) ol[e] = f2bf(f[e] * sc * wf[e]);
        *(uint2*)&hb[(size_t)row * DMODEL + tid * 4] = *(uint2*)ol;
        return;
    }
    const float* in; us* out; int K, N, nt, kt;
    if (tb < 4096) {
        int w = tb >> 10, u = tb & 1023;
        in = (w == 0) ? wq : (w == 1) ? wk : (w == 2) ? wv : wo;
        out = (w < 3) ? (wqkvt + (size_t)w * 1024 * 1024) : wot;
        K = 1024; N = 1024; nt = (u & 31) * 32; kt = (u >> 5) * 32;
    } else if (tb < 8192) {
        int u = tb - 4096;
        in = w1; out = w1t; K = 1024; N = 4096; nt = (u & 127) * 32; kt = (u >> 7) * 32;
    } else {
        int u = tb - 8192;
        in = w2; out = w2t; K = 4096; N = 1024; nt = (u & 31) * 32; kt = (u >> 5) * 32;
    }
    for (int i = 0; i < 4; ++i)
        tile[ty + 8 * i][tx] = f2bf(in[(size_t)(kt + ty + 8 * i) * N + nt + tx]);
    __syncthreads();
    for (int i = 0; i < 4; ++i)
        out[(size_t)(nt + ty + 8 * i) * K + kt + tx] = tile[tx][ty + 8 * i];
}

// ---------------- bf16 transpose: V (strided rows) -> Vt [B*D][T], key-permuted ---------
// Within each 64-key block, key k is stored at col sigma(k) = ((k&15)<<2)|((k&63)>>4).
// Matches the packed P storage in attn (storage col c holds key pi(c)=(c&3)*16+(c>>2);
// pi = sigma^-1), so the PV contraction sees identical key order on both operands.
__global__ void vtrans_k(const us* __restrict__ in, us* __restrict__ out, int istride) {
    __shared__ us tile[32][33];
    int b = blockIdx.z;
    int ct = blockIdx.x * 32;   // D tile
    int rt = blockIdx.y * 32;   // T tile
    int tx = threadIdx.x, ty = threadIdx.y; // (32,8)
    for (int i = 0; i < 4; ++i)
        tile[ty + 8 * i][tx] = in[((size_t)b * TSEQ + rt + ty + 8 * i) * istride + ct + tx];
    __syncthreads();
    int tt = rt + tx;
    int ts = (tt & ~63) | ((tt & 15) << 2) | ((tt & 63) >> 4);
    for (int i = 0; i < 4; ++i)
        out[((size_t)b * DMODEL + ct + ty + 8 * i) * TSEQ + ts] = tile[tx][ty + 8 * i];
}

// ---------------- Residual + RMSNorm: out = rmsnorm(a + b [+ b2]) * w ----------------
// NOTE: out may alias a (row-local) -> no __restrict__.
__global__ void resnorm_k(const us* a, const us* b,
                          const us* b2,
                          const float* w,
                          void* outp, int out_f32) {
    int row = blockIdx.x, t = threadIdx.x;
    us al[4], bl[4], cl[4];
    *(uint2*)al = *(const uint2*)&a[(size_t)row * DMODEL + t * 4];
    *(uint2*)bl = *(const uint2*)&b[(size_t)row * DMODEL + t * 4];
    if (b2) *(uint2*)cl = *(const uint2*)&b2[(size_t)row * DMODEL + t * 4];
    float f[4];
    float ss = 0.f;
    for (int e = 0; e < 4; ++e) {
        f[e] = bf2f(al[e]) + bf2f(bl[e]);
        if (b2) f[e] += bf2f(cl[e]);
        ss += f[e] * f[e];
    }
    for (int m = 1; m < 64; m <<= 1) ss += __shfl_xor(ss, m);
    __shared__ float red[4];
    if ((t & 63) == 0) red[t >> 6] = ss;
    __syncthreads();
    float tot = red[0] + red[1] + red[2] + red[3];
    float sc = rsqrtf(tot * (1.f / DMODEL) + 1e-6f);
    float4 wv = *(const float4*)&w[t * 4];
    float wf[4] = {wv.x, wv.y, wv.z, wv.w};
    if (out_f32) {
        float4 ov;
        ov.x = f[0] * sc * wf[0]; ov.y = f[1] * sc * wf[1];
        ov.z = f[2] * sc * wf[2]; ov.w = f[3] * sc * wf[3];
        *(float4*)&((float*)outp)[(size_t)row * DMODEL + t * 4] = ov;
    } else {
        us ol[4];
        for (int e = 0; e < 4; ++e) ol[e] = f2bf(f[e] * sc * wf[e]);
        *(uint2*)&((us*)outp)[(size_t)row * DMODEL + t * 4] = *(uint2*)ol;
    }
}

// ---------------- Residual + RMSNorm over 4 split-K partials (f32 out) ----------------
__global__ void resnorm4_k(const us* __restrict__ a, const us* __restrict__ p,
                           size_t pstride, const float* __restrict__ w,
                           float* __restrict__ out) {
    int row = blockIdx.x, t = threadIdx.x;
    size_t off = (size_t)row * DMODEL + t * 4;
    us al[4], pl[4][4];
    *(uint2*)al = *(const uint2*)&a[off];
#pragma unroll
    for (int z = 0; z < 4; ++z)
        *(uint2*)pl[z] = *(const uint2*)&p[off + z * pstride];
    float f[4];
    float ss = 0.f;
#pragma unroll
    for (int e = 0; e < 4; ++e) {
        f[e] = bf2f(al[e]) + bf2f(pl[0][e]) + bf2f(pl[1][e]) + bf2f(pl[2][e]) + bf2f(pl[3][e]);
        ss += f[e] * f[e];
    }
    for (int m = 1; m < 64; m <<= 1) ss += __shfl_xor(ss, m);
    __shared__ float red[4];
    if ((t & 63) == 0) red[t >> 6] = ss;
    __syncthreads();
    float tot = red[0] + red[1] + red[2] + red[3];
    float sc = rsqrtf(tot * (1.f / DMODEL) + 1e-6f);
    float4 wv = *(const float4*)&w[t * 4];
    float4 ov;
    ov.x = f[0] * sc * wv.x; ov.y = f[1] * sc * wv.y;
    ov.z = f[2] * sc * wv.z; ov.w = f[3] * sc * wv.w;
    *(float4*)&out[off] = ov;
}

// ---------------- legacy 128-tile 2-phase GEMM (kept for O-proj: short K, small) -------
template<int BN, int GX, bool SWZ>
__global__ __launch_bounds__(256, (BN == 256) ? 2 : 4)
void gemm_dbuf_k(const us* __restrict__ A,
                 const us* __restrict__ Bt,
                 us* __restrict__ C,
                 int M, int N, int K, int do_silu,
                 int Ks, size_t cstride) {
    constexpr int MI = 4, NI = BN / 32;
    constexpr int BDMA = BN / 64;
    __shared__ __align__(16) us As[2][128 * 32];
    __shared__ __align__(16) us Bs[2][BN * 32];
    int t = threadIdx.x;
    int n0 = blockIdx.x;
    int bx, by, z;
    if (SWZ) {
        int c = n0 & 7, bb = n0 >> 3;
        bx = bb % GX;
        int g = bb / GX;
        int yz = c + 8 * g;
        by = yz & 31; z = yz >> 5;
    } else {
        bx = n0 % GX;
        int bb = n0 / GX;
        by = bb & 31; z = bb >> 5;
    }
    int bm = by * 128, bn = bx * BN;
    int lane = t & 63, wave = t >> 6;
    int wm = (wave & 1) * 64, wn = (wave >> 1) * (BN / 2);
    int lr = lane & 15, lq = lane >> 4;

    int sr = lane >> 2;
    int sc = (((lane & 3) ^ ((lane >> 3) & 3)) * 8);
    const us* gA = A + (size_t)(bm + wave * 32 + sr) * K + sc + (size_t)z * Ks;
    const us* gB = Bt + (size_t)(bn + wave * (BN / 4) + sr) * K + sc + (size_t)z * Ks;
    const int aoff = (wave * 32) * 32;
    const int boff = (wave * (BN / 4)) * 32;
    C += (size_t)z * cstride;

    floatx4 acc[MI][NI];
#pragma unroll
    for (int mi = 0; mi < MI; ++mi)
#pragma unroll
        for (int ni = 0; ni < NI; ++ni)
            acc[mi][ni] = (floatx4){0.f, 0.f, 0.f, 0.f};

#pragma unroll
    for (int i = 0; i < 2; ++i)
        gld_lds16(gA + (size_t)(16 * i) * K, &As[0][aoff + i * 16 * 32]);
#pragma unroll
    for (int i = 0; i < BDMA; ++i)
        gld_lds16(gB + (size_t)(16 * i) * K, &Bs[0][boff + i * 16 * 32]);

    int aslot = ((lq ^ ((lr >> 1) & 3)) << 3);

    int nk = Ks >> 5;
    for (int kk = 0; kk < nk; ++kk) {
        __syncthreads();
        int cur = kk & 1, nxt = cur ^ 1;
        if (kk + 1 < nk) {
            size_t off = (size_t)(kk + 1) * 32;
#pragma unroll
            for (int i = 0; i < 2; ++i)
                gld_lds16(gA + (size_t)(16 * i) * K + off, &As[nxt][aoff + i * 16 * 32]);
#pragma unroll
            for (int i = 0; i < BDMA; ++i)
                gld_lds16(gB + (size_t)(16 * i) * K + off, &Bs[nxt][boff + i * 16 * 32]);
        }
        short8 a[MI], b[NI];
#pragma unroll
        for (int mi = 0; mi < MI; ++mi)
            a[mi] = *(const short8*)&As[cur][(wm + mi * 16 + lr) * 32 + aslot];
#pragma unroll
        for (int ni = 0; ni < NI; ++ni)
            b[ni] = *(const short8*)&Bs[cur][(wn + ni * 16 + lr) * 32 + aslot];
#pragma unroll
        for (int mi = 0; mi < MI; ++mi)
#pragma unroll
            for (int ni = 0; ni < NI; ++ni)
                acc[mi][ni] = __builtin_amdgcn_mfma_f32_16x16x32_bf16(a[mi], b[ni], acc[mi][ni], 0, 0, 0);
    }

#pragma unroll
    for (int mi = 0; mi < MI; ++mi)
#pragma unroll
        for (int ni = 0; ni < NI; ++ni)
#pragma unroll
            for (int r = 0; r < 4; ++r) {
                int m = bm + wm + mi * 16 + lq * 4 + r;
                int nn = bn + wn + ni * 16 + lr;
                float v = acc[mi][ni][r];
                if (do_silu) v = v / (1.f + __expf(-v));
                C[(size_t)m * N + nn] = f2bf(v);
            }
}

// ================= R19: 256x256 4-phase GEMM, VALU-lean addressing =======================
// Schedule identical to R18 (refcheck'd). Codegen changes only:
//  - staging via 4 induction pointers (ga0/ga1/gb0/gb1), advanced +64 elem per staged tile
//    (no runtime 64-bit muls in the loop)
//  - LDS reads via 8 precomputed base pointers + compile-time immediate offsets
//    (single ds_read_b128 offset:N each)
// Evidence: R18 VALUBusy 28% = ~180 VALU/wave/phase of address recompute at 2 waves/SIMD,
// serializing with lgkm drain + MFMA issue (m33 pattern, exposed at 1 block/CU).

#define BAR8 __builtin_amdgcn_s_barrier()
#define WLGKM do { asm volatile("s_waitcnt lgkmcnt(0)" ::: "memory"); \
                   __builtin_amdgcn_sched_barrier(0); } while (0)
#define VM4 do { asm volatile("s_waitcnt vmcnt(4)" ::: "memory"); } while (0)
#define VM0 do { asm volatile("s_waitcnt vmcnt(0)" ::: "memory"); } while (0)

template<int GX>
__global__ __launch_bounds__(512, 2)
void gemm8p_k(const us* __restrict__ A, const us* __restrict__ Bt, us* __restrict__ C,
              int N, int K, int Ks, int do_silu, size_t cstride) {
    __shared__ __align__(16) us Alds[2 * 2 * 128 * 64];   // 64 KiB
    __shared__ __align__(16) us Blds[2 * 2 * 128 * 64];   // 64 KiB
    int t = threadIdx.x, lane = t & 63, wave = t >> 6;
    int n0 = blockIdx.x;
    int by = n0 & 15, rest = n0 >> 4;       // M=4096 fixed -> 16 row-blocks
    int bx = rest % GX, z = rest / GX;
    int bm = by * 256, bn = bx * 256;
    int lr = lane & 15, lq = (lane >> 4) & 3;
    int wm2 = wave >> 2, wn2 = wave & 3;

    // staging induction pointers (pre-swizzled chunk: LDS[row][c] = G[row][c ^ (row&7)])
    const size_t r8 = (size_t)8 * K;        // +8 rows
    const us* ga0 = A + (size_t)(bm + wave * 16 + (lane >> 3)) * K
                      + ((lane & 7) ^ (lane >> 3)) * 8 + (size_t)z * Ks;
    const us* ga1 = ga0 + (size_t)128 * K;  // h1 half
    const us* gb0 = Bt + (size_t)(bn + wave * 16 + (lane >> 3)) * K
                       + ((lane & 7) ^ (lane >> 3)) * 8 + (size_t)z * Ks;
    const us* gb1 = gb0 + (size_t)128 * K;
    const int sd = wave * 1024;             // wave's 16 rows x 64 within a half
    C += (size_t)z * cstride;

    // LDS read bases: slot = chunk ^ (row&7); ksub0 -> sw0, ksub1 -> sw1
    const int sw0 = ((lq ^ (lr & 7)) * 8);
    const int sw1 = (((4 + lq) ^ (lr & 7)) * 8);
    const us* pa00 = &Alds[wm2 * 8192 + lr * 64 + sw0];
    const us* pa01 = &Alds[wm2 * 8192 + lr * 64 + sw1];
    const us* pa10 = pa00 + 16384;
    const us* pa11 = pa01 + 16384;
    const int bo = (wn2 >> 1) * 8192 + (wn2 & 1) * 4096 + lr * 64;
    const us* pb00 = &Blds[bo + sw0];
    const us* pb01 = &Blds[bo + sw1];
    const us* pb10 = pb00 + 16384;
    const us* pb11 = pb01 + 16384;
    // LDS stage dests (wave-uniform)
    us* dA0h0 = &Alds[sd];          us* dA0h1 = &Alds[8192 + sd];
    us* dA1h0 = &Alds[16384 + sd];  us* dA1h1 = &Alds[16384 + 8192 + sd];
    us* dB0h0 = &Blds[sd];          us* dB0h1 = &Blds[8192 + sd];
    us* dB1h0 = &Blds[16384 + sd];  us* dB1h1 = &Blds[16384 + 8192 + sd];

#define STG_A2(d) do { \
    gld_lds16(ga0,      dA##d##h0); gld_lds16(ga0 + r8, dA##d##h0 + 512); \
    gld_lds16(ga1,      dA##d##h1); gld_lds16(ga1 + r8, dA##d##h1 + 512); \
    ga0 += 64; ga1 += 64; } while (0)
#define STG_B2(d) do { \
    gld_lds16(gb0,      dB##d##h0); gld_lds16(gb0 + r8, dB##d##h0 + 512); \
    gld_lds16(gb1,      dB##d##h1); gld_lds16(gb1 + r8, dB##d##h1 + 512); \
    gb0 += 64; gb1 += 64; } while (0)
#define RDA(sl, mf, D) do { \
    aF[sl][0] = *(const short8*)(pa##D##0 + (mf) * 1024); \
    aF[sl][1] = *(const short8*)(pa##D##1 + (mf) * 1024); } while (0)
#define RDB(nf, D) do { \
    bF[nf][0] = *(const short8*)(pb##D##0 + (nf) * 1024); \
    bF[nf][1] = *(const short8*)(pb##D##1 + (nf) * 1024); } while (0)
#define MMROW(mf, sl) do { \
    acc[mf][0] = __builtin_amdgcn_mfma_f32_16x16x32_bf16(aF[sl][0], bF[0][0], acc[mf][0], 0, 0, 0); \
    acc[mf][1] = __builtin_amdgcn_mfma_f32_16x16x32_bf16(aF[sl][0], bF[1][0], acc[mf][1], 0, 0, 0); \
    acc[mf][2] = __builtin_amdgcn_mfma_f32_16x16x32_bf16(aF[sl][0], bF[2][0], acc[mf][2], 0, 0, 0); \
    acc[mf][3] = __builtin_amdgcn_mfma_f32_16x16x32_bf16(aF[sl][0], bF[3][0], acc[mf][3], 0, 0, 0); \
    acc[mf][0] = __builtin_amdgcn_mfma_f32_16x16x32_bf16(aF[sl][1], bF[0][1], acc[mf][0], 0, 0, 0); \
    acc[mf][1] = __builtin_amdgcn_mfma_f32_16x16x32_bf16(aF[sl][1], bF[1][1], acc[mf][1], 0, 0, 0); \
    acc[mf][2] = __builtin_amdgcn_mfma_f32_16x16x32_bf16(aF[sl][1], bF[2][1], acc[mf][2], 0, 0, 0); \
    acc[mf][3] = __builtin_amdgcn_mfma_f32_16x16x32_bf16(aF[sl][1], bF[3][1], acc[mf][3], 0, 0, 0); } while (0)
#define PRIO1 __builtin_amdgcn_s_setprio(1)
#define PRIO0 __builtin_amdgcn_s_setprio(0)

    floatx4 acc[8][4];
#pragma unroll
    for (int mf = 0; mf < 8; ++mf)
#pragma unroll
        for (int nf = 0; nf < 4; ++nf)
            acc[mf][nf] = (floatx4){0.f, 0.f, 0.f, 0.f};

    short8 aF[4][2], bF[4][2];

    // prologue: tile0 complete + tile1 B halves. 12 loads; VM4 -> tile0 landed,
    // 4 outstanding (T1.B) = loop invariant.
    STG_B2(0); STG_A2(0); STG_B2(1);
    VM4; BAR8;

    const int NK2 = Ks >> 7;               // (Ks/64)/2 pairs; Ks=1024 -> 8
    for (int i = 0; i < NK2 - 1; ++i) {
        // Q1 (tile 2i, buf0): B all + A mf0-3; stage T(2i+1).A -> buf1.A (idle)
        RDB(0, 0); RDB(1, 0); RDB(2, 0); RDB(3, 0);
        RDA(0, 0, 0); RDA(1, 1, 0); RDA(2, 2, 0); RDA(3, 3, 0);
        STG_A2(1);
        BAR8; WLGKM; PRIO1; MMROW(0, 0); MMROW(1, 1); MMROW(2, 2); MMROW(3, 3); PRIO0; BAR8;
        // Q2: A mf4-7; stage T(2i+2).B -> buf0.B (read done Q1); VM4 proves T(2i+1) landed
        RDA(0, 4, 0); RDA(1, 5, 0); RDA(2, 6, 0); RDA(3, 7, 0);
        STG_B2(0);
        VM4; BAR8; WLGKM; PRIO1; MMROW(4, 0); MMROW(5, 1); MMROW(6, 2); MMROW(7, 3); PRIO0; BAR8;
        // Q3 (tile 2i+1, buf1): B all + A mf0-3; stage T(2i+2).A -> buf0.A (read done Q2)
        RDB(0, 1); RDB(1, 1); RDB(2, 1); RDB(3, 1);
        RDA(0, 0, 1); RDA(1, 1, 1); RDA(2, 2, 1); RDA(3, 3, 1);
        STG_A2(0);
        BAR8; WLGKM; PRIO1; MMROW(0, 0); MMROW(1, 1); MMROW(2, 2); MMROW(3, 3); PRIO0; BAR8;
        // Q4: A mf4-7; stage T(2i+3).B -> buf1.B (read done Q3); VM4 proves T(2i+2) landed
        RDA(0, 4, 1); RDA(1, 5, 1); RDA(2, 6, 1); RDA(3, 7, 1);
        STG_B2(1);
        VM4; BAR8; WLGKM; PRIO1; MMROW(4, 0); MMROW(5, 1); MMROW(6, 2); MMROW(7, 3); PRIO0; BAR8;
    }
    {   // peeled last pair: only T(2*NK2-1).A still needs staging (Q1); drain fully at Q2
        RDB(0, 0); RDB(1, 0); RDB(2, 0); RDB(3, 0);
        RDA(0, 0, 0); RDA(1, 1, 0); RDA(2, 2, 0); RDA(3, 3, 0);
        STG_A2(1);
        BAR8; WLGKM; PRIO1; MMROW(0, 0); MMROW(1, 1); MMROW(2, 2); MMROW(3, 3); PRIO0; BAR8;
        RDA(0, 4, 0); RDA(1, 5, 0); RDA(2, 6, 0); RDA(3, 7, 0);
        VM0; BAR8; WLGKM; PRIO1; MMROW(4, 0); MMROW(5, 1); MMROW(6, 2); MMROW(7, 3); PRIO0; BAR8;
        // last tile (buf1), fully staged
        RDB(0, 1); RDB(1, 1); RDB(2, 1); RDB(3, 1);
        RDA(0, 0, 1); RDA(1, 1, 1); RDA(2, 2, 1); RDA(3, 3, 1);
        BAR8; WLGKM; PRIO1; MMROW(0, 0); MMROW(1, 1); MMROW(2, 2); MMROW(3, 3); PRIO0; BAR8;
        RDA(0, 4, 1); RDA(1, 5, 1); RDA(2, 6, 1); RDA(3, 7, 1);
        WLGKM; PRIO1; MMROW(4, 0); MMROW(5, 1); MMROW(6, 2); MMROW(7, 3); PRIO0;
    }

    // epilogue: C/D layout col = lane&15, row = (lane>>4)*4 + r
    int cm = bm + wm2 * 128, cn = bn + wn2 * 64;
#pragma unroll
    for (int mf = 0; mf < 8; ++mf)
#pragma unroll
        for (int nf = 0; nf < 4; ++nf)
#pragma unroll
            for (int r = 0; r < 4; ++r) {
                int m = cm + mf * 16 + lq * 4 + r;
                int nn = cn + nf * 16 + lr;
                float v = acc[mf][nf][r];
                if (do_silu) v = v / (1.f + __expf(-v));
                C[(size_t)m * N + nn] = f2bf(v);
            }
#undef STG_A2
#undef STG_B2
#undef RDA
#undef RDB
#undef MMROW
#undef PRIO1
#undef PRIO0
}

// ================= Flash attention: 512-thread blocks, 2 q-tiles sharing one K/V pass ======
// R17: P materialized via truncating bit-pack + ds_write_b64 (short4v, same TBAA class as
// the short8 reload) + explicit lgkmcnt(0)+sched_barrier fence before the PV reads.
// P storage col c holds key pi(c)=(c&3)*16+(c>>2); V is pre-permuted by sigma=pi^-1
// in vtrans_k so PV k-slots line up.
#define PSTR 72

template<bool DIAG>
__device__ __forceinline__ void flash_tile_nm(
    const short8& qf0, const short8& qf1,
    floatx4* oa, float* lrw,
    const us* Ks, const us* Vts, us* Ps, const short8& ones,
    int lr, int lq, int sub)
{
    floatx4 s[4];
#pragma unroll
    for (int n = 0; n < 4; ++n) {
        int R = n * 16 + lr;
        short8 kf0 = *(const short8*)&Ks[R * 64 + ((lq ^ (R & 7)) << 3)];
        short8 kf1 = *(const short8*)&Ks[R * 64 + (((lq + 4) ^ (R & 7)) << 3)];
        floatx4 z = (floatx4){0.f, 0.f, 0.f, 0.f};
        z = __builtin_amdgcn_mfma_f32_16x16x32_bf16(qf0, kf0, z, 0, 0, 0);
        s[n] = __builtin_amdgcn_mfma_f32_16x16x32_bf16(qf1, kf1, z, 0, 0, 0);
    }
    if (DIAG) {
#pragma unroll
        for (int n = 0; n < 4; ++n)
#pragma unroll
            for (int r = 0; r < 4; ++r)
                if ((n * 16 + lr) > (sub * 16 + lq * 4 + r)) s[n][r] = -1e30f;  // exp2 -> 0
    }
    // packed P write: keys {n*16+lr} -> storage cols lr*4+n (pi-permuted layout)
#pragma unroll
    for (int r = 0; r < 4; ++r) {
        union { unsigned int u[2]; short4v v; } pk;
        pk.u[0] = pk_trunc(__builtin_amdgcn_exp2f(s[0][r]), __builtin_amdgcn_exp2f(s[1][r]));
        pk.u[1] = pk_trunc(__builtin_amdgcn_exp2f(s[2][r]), __builtin_amdgcn_exp2f(s[3][r]));
        *(short4v*)&Ps[(lq * 4 + r) * PSTR + lr * 4] = pk.v;
    }
    // ensure the 4 ds_write_b64 above complete before the same wave's ds_reads below
    asm volatile("s_waitcnt lgkmcnt(0)" ::: "memory");
    __builtin_amdgcn_sched_barrier(0);

    floatx4 zs = (floatx4){0.f, 0.f, 0.f, 0.f};
    __builtin_amdgcn_s_setprio(1);
#pragma unroll
    for (int kx = 0; kx < 2; ++kx) {
        short8 pf = *(const short8*)&Ps[lr * PSTR + kx * 32 + lq * 8];
        zs = __builtin_amdgcn_mfma_f32_16x16x32_bf16(pf, ones, zs, 0, 0, 0);
#pragma unroll
        for (int nd = 0; nd < 4; ++nd) {
            int R = nd * 16 + lr;
            short8 vf = *(const short8*)&Vts[R * 64 + ((((kx << 2) | lq) ^ (R & 7)) << 3)];
            oa[nd] = __builtin_amdgcn_mfma_f32_16x16x32_bf16(pf, vf, oa[nd], 0, 0, 0);
        }
    }
    __builtin_amdgcn_s_setprio(0);
#pragma unroll
    for (int r = 0; r < 4; ++r) lrw[r] += zs[r];
}

__global__ __launch_bounds__(512, 6) void attn_k(const us* __restrict__ q,
                                                 const us* __restrict__ kg,
                                                 const us* __restrict__ vt,
                                                 us* __restrict__ o,
                                                 us* __restrict__ Po,
                                                 float* __restrict__ Pl) {
    __shared__ __align__(16) us Ks[2][64 * 64];
    __shared__ __align__(16) us Vts[2][64 * 64];
    __shared__ __align__(16) us Ps[8 * 16 * PSTR];
    int j = blockIdx.x;
    int part = (j >= 16);
    int P = part ? (j - 8) : j;
    int qtA = 2 * P, qtB = 2 * P + 1;
    int k0 = part ? 16 : 0;
    int k1 = part ? qtB : (qtB < 15 ? qtB : 15);
    bool fin = (!part) && (P < 8);
    int bh = blockIdx.y;
    int b = bh >> 4, h = bh & 15;
    size_t base = (size_t)b * TSEQ;
    const us* vth = vt + ((size_t)b * DMODEL + h * 64) * TSEQ;
    int t = threadIdx.x, lane = t & 63, wave = t >> 6;   // wave 0..7
    int sub = wave & 3, grp = wave >> 2;                 // strip index, q-tile group
    int myqt = grp ? qtB : qtA;
    int lr = lane & 15, lq = lane >> 4;

    const float SC = 0.18033688011112042f;  // (1/8)*log2(e)
    int qrow = myqt * 64 + sub * 16 + lr;
    short8 qf0 = *(const short8*)&q[(base + qrow) * QKVS + h * 64 + lq * 8];
    short8 qf1 = *(const short8*)&q[(base + qrow) * QKVS + h * 64 + 32 + lq * 8];
#pragma unroll
    for (int e = 0; e < 8; ++e) {
        qf0[e] = (short)f2bf(bf2f((us)qf0[e]) * SC);
        qf1[e] = (short)f2bf(bf2f((us)qf1[e]) * SC);
    }
    short8 ones;
#pragma unroll
    for (int e = 0; e < 8; ++e) ones[e] = (short)0x3F80;  // bf16 1.0

    us* Psw = &Ps[wave * 16 * PSTR];

    floatx4 oa[4];
    float lrw[4] = {0.f, 0.f, 0.f, 0.f};
#pragma unroll
    for (int i = 0; i < 4; ++i) oa[i] = (floatx4){0.f, 0.f, 0.f, 0.f};

    int rsub = lane >> 3;
    int cda = ((lane & 7) ^ rsub) * 8;
    const us* gK = kg + (base + wave * 8 + rsub) * QKVS + h * 64 + cda;
    const us* gV = vth + (size_t)(wave * 8 + rsub) * TSEQ + cda;

    gld_lds16(gK + (size_t)(k0 * 64) * QKVS, &Ks[0][(wave * 8) * 64]);
    gld_lds16(gV + k0 * 64, &Vts[0][(wave * 8) * 64]);

    for (int kt = k0; kt <= k1; ++kt) {
        __syncthreads();
        int cur = (kt - k0) & 1, nxt = cur ^ 1;
        if (kt < k1) {
            gld_lds16(gK + (size_t)((kt + 1) * 64) * QKVS, &Ks[nxt][(wave * 8) * 64]);
            gld_lds16(gV + (kt + 1) * 64, &Vts[nxt][(wave * 8) * 64]);
        }
        if (kt <= myqt) {
            if (kt == myqt)
                flash_tile_nm<true>(qf0, qf1, oa, lrw, Ks[cur], Vts[cur], Psw, ones, lr, lq, sub);
            else
                flash_tile_nm<false>(qf0, qf1, oa, lrw, Ks[cur], Vts[cur], Psw, ones, lr, lq, sub);
        }
    }

    if (fin) {
#pragma unroll
        for (int nd = 0; nd < 4; ++nd)
#pragma unroll
            for (int r = 0; r < 4; ++r) {
                int tok = myqt * 64 + sub * 16 + lq * 4 + r;
                o[(base + tok) * DMODEL + h * 64 + nd * 16 + lr] = f2bf(oa[nd][r] / lrw[r]);
            }
    } else {
#pragma unroll
        for (int nd = 0; nd < 4; ++nd)
#pragma unroll
            for (int r = 0; r < 4; ++r) {
                int tok = myqt * 64 + sub * 16 + lq * 4 + r;
                size_t pb = ((size_t)(part * BATCH + b) * 1024 + (tok - 1024)) * 1024;
                Po[pb + h * 64 + nd * 16 + lr] = f2bf(oa[nd][r]);
            }
        if (lr == 0) {
#pragma unroll
            for (int r = 0; r < 4; ++r) {
                int tok = myqt * 64 + sub * 16 + lq * 4 + r;
                Pl[((part * BATCH + b) * NHEADS + h) * TSEQ + tok] = lrw[r];
            }
        }
    }
}

__global__ void merge_k(const us* __restrict__ Po, const float* __restrict__ Pl,
                        us* __restrict__ ab) {
    int row = blockIdx.x;            // 0..2047
    int b = row >> 10, tloc = row & 1023;
    int t = 1024 + tloc;
    int t4 = threadIdx.x * 4;
    int h = t4 >> 6;
    float l0 = Pl[((0 * BATCH + b) * NHEADS + h) * TSEQ + t];
    float l1 = Pl[((1 * BATCH + b) * NHEADS + h) * TSEQ + t];
    float inv = 1.f / (l0 + l1);
    size_t o0 = ((size_t)(0 * BATCH + b) * 1024 + tloc) * 1024 + t4;
    size_t o1 = ((size_t)(1 * BATCH + b) * 1024 + tloc) * 1024 + t4;
    us p0[4], p1[4], ol[4];
    *(uint2*)p0 = *(const uint2*)&Po[o0];
    *(uint2*)p1 = *(const uint2*)&Po[o1];
    for (int e = 0; e < 4; ++e)
        ol[e] = f2bf((bf2f(p0[e]) + bf2f(p1[e])) * inv);
    *(uint2*)&ab[((size_t)b * TSEQ + t) * DMODEL + t4] = *(uint2*)ol;
}

// ---------------- launch ----------------
extern "C" void kernel_launch(void* const* d_in, const int* in_sizes, int n_in,
                              void* d_out, int out_size, void* d_ws, size_t ws_size,
                              hipStream_t stream) {
    const float* x      = (const float*)d_in[0];
    const float* w_pre  = (const float*)d_in[1];
    const float* wq     = (const float*)d_in[2];
    const float* wk     = (const float*)d_in[3];
    const float* wv     = (const float*)d_in[4];
    const float* wo     = (const float*)d_in[5];
    const float* w_attn = (const float*)d_in[6];
    const float* w1     = (const float*)d_in[7];
    const float* w2     = (const float*)d_in[8];
    const float* w_ffn  = (const float*)d_in[9];

    char* ws = (char*)d_ws;
    const size_t MB = 1024 * 1024;
    us* hb    = (us*)(ws + 0);
    us* qkvb  = (us*)(ws + 8 * MB);
    us* ab    = (us*)(ws + 32 * MB);
    us* vtb   = (us*)(ws + 40 * MB);
    us* ob0   = (us*)(ws + 40 * MB);
    us* ob1   = (us*)(ws + 48 * MB);
    us* Pob   = (us*)(ws + 48 * MB);
    us* yb    = (us*)(ws + 0);        // in-place over hb (row-local safe)
    us* wqkvt = (us*)(ws + 56 * MB);  // 6 MB
    us* wot   = (us*)(ws + 62 * MB);  // 2 MB
    us* w1t   = (us*)(ws + 64 * MB);  // 8 MB
    us* w2t   = (us*)(ws + 72 * MB);  // 8 MB
    float* Pl = (float*)(ws + 80 * MB); // 1 MB
    us* midb  = (us*)(ws + 8 * MB);   // 32 MB FFN mid (qkvb+ab dead)
    us* fb0   = (us*)(ws + 40 * MB);  // FFN2 split-K=4 partials, 8 MB stride
    const size_t FB_STR = (8 * MB) / 2;

    dim3 tb(32, 8);
    // R19: 6 transposes + pre-norm in one launch (12288 tiles + 4096 rows)
    prologue_k<<<dim3(16384), tb, 0, stream>>>(
        wq, wk, wv, wo, w1, w2, x, w_pre, wqkvt, wot, w1t, w2t, hb);

    // fused QKV: 4-phase 256x256, 16x12 = 192 blocks
    gemm8p_k<12><<<dim3(192), 512, 0, stream>>>(
        hb, wqkvt, qkvb, QKVS, DMODEL, DMODEL, 0, 0);

    vtrans_k<<<dim3(DMODEL / 32, TSEQ / 32, BATCH), tb, 0, stream>>>(qkvb + 2048, vtb, QKVS);

    attn_k<<<dim3(24, BATCH * NHEADS), 512, 0, stream>>>(qkvb, qkvb + 1024, vtb, ab, Pob, Pl);
    merge_k<<<dim3(BATCH * 1024), 256, 0, stream>>>(Pob, Pl, ab);

    // O-proj: legacy 2-phase, GX=8, split-K=2 -> 512 blocks (short K; small op)
    gemm_dbuf_k<128, 8, true><<<dim3(512), 256, 0, stream>>>(
        ab, wot, ob0, BT, DMODEL, DMODEL, 0, DMODEL / 2, (size_t)BT * DMODEL);
    resnorm_k<<<BT, 256, 0, stream>>>(hb, ob0, ob1, w_attn, yb, 0);

    // FFN1: 4-phase 256x256, 16x16 = 256 blocks, fused silu
    gemm8p_k<16><<<dim3(256), 512, 0, stream>>>(
        yb, w1t, midb, FFDIM, DMODEL, DMODEL, 1, 0);
    // FFN2: 4-phase 256x256, split-K=4 -> 16x4x4 = 256 blocks, Ks=1024
    gemm8p_k<4><<<dim3(256), 512, 0, stream>>>(
        midb, w2t, fb0, DMODEL, FFDIM, FFDIM / 4, 0, FB_STR);
    resnorm4_k<<<BT, 256, 0, stream>>>(yb, fb0, FB_STR, w_ffn, (float*)d_out);
}

// Round 8
// 306.351 us; speedup vs baseline: 1.1005x; 1.0339x over previous
//
#include <hip/hip_runtime.h>
#include <cstdint>
#include <cstddef>

#define TSEQ   2048
#define BATCH  2
#define BT     4096      // BATCH*TSEQ
#define DMODEL 1024
#define NHEADS 16
#define HDIM   64
#define FFDIM  4096
#define QKVS   3072      // row stride of fused qkv buffer

typedef __attribute__((ext_vector_type(8))) short short8;    // 8 bf16 = 4 VGPRs
typedef __attribute__((ext_vector_type(4))) short short4v;   // 8B of bf16
typedef __attribute__((ext_vector_type(4))) float floatx4;   // MFMA acc
typedef unsigned short us;

__device__ __forceinline__ float bf2f(us u) {
    union { unsigned int i; float f; } v; v.i = ((unsigned int)u) << 16; return v.f;
}
__device__ __forceinline__ us f2bf(float f) {
    union { float f; unsigned int i; } v; v.f = f;
    unsigned int r = v.i + 0x7fffu + ((v.i >> 16) & 1u);
    return (us)(r >> 16);
}
__device__ __forceinline__ unsigned int fbits(float f) {
    union { float f; unsigned int u; } v; v.f = f; return v.u;
}
// pack two f32 -> two bf16 (truncating; P in [0,1] so <=1 ULP down). lo -> low half.
__device__ __forceinline__ unsigned int pk_trunc(float lo, float hi) {
    return (fbits(hi) & 0xffff0000u) | (fbits(lo) >> 16);
}

// async global->LDS, 16B per lane. LDS dest = wave-uniform base + lane*16.
__device__ __forceinline__ void gld_lds16(const us* g, us* l) {
    __builtin_amdgcn_global_load_lds(
        (const __attribute__((address_space(1))) uint32_t*)(const void*)g,
        (__attribute__((address_space(3))) uint32_t*)(void*)l, 16, 0, 0);
}

// ============ prologue: 6 weight transposes + pre-norm fused into one launch =========
// blocks [0,12288): 32x32 transpose tiles (wq,wk,wv,wo: 4x1024 | w1: 4096 | w2: 4096)
// blocks [12288,16384): rmsnorm rows. All branches are block-uniform.
__global__ void prologue_k(const float* __restrict__ wq, const float* __restrict__ wk,
                           const float* __restrict__ wv, const float* __restrict__ wo,
                           const float* __restrict__ w1, const float* __restrict__ w2,
                           const float* __restrict__ x,  const float* __restrict__ w_pre,
                           us* __restrict__ wqkvt, us* __restrict__ wot,
                           us* __restrict__ w1t, us* __restrict__ w2t,
                           us* __restrict__ hb) {
    __shared__ us tile[32][33];
    __shared__ float red[4];
    int tb = blockIdx.x;
    int tx = threadIdx.x, ty = threadIdx.y;  // (32,8)
    if (tb >= 12288) {                        // ---- rmsnorm row ----
        int row = tb - 12288;
        int tid = ty * 32 + tx;
        float4 xv = *(const float4*)&x[(size_t)row * DMODEL + tid * 4];
        float f[4] = {xv.x, xv.y, xv.z, xv.w};
        float ss = 0.f;
        for (int e = 0; e < 4; ++e) ss += f[e] * f[e];
        for (int m = 1; m < 64; m <<= 1) ss += __shfl_xor(ss, m);
        if ((tid & 63) == 0) red[tid >> 6] = ss;
        __syncthreads();
        float tot = red[0] + red[1] + red[2] + red[3];
        float sc = rsqrtf(tot * (1.f / DMODEL) + 1e-6f);
        float4 wv4 = *(const float4*)&w_pre[tid * 4];
        float wf[4] = {wv4.x, wv4.y, wv4.z, wv4.w};
        us ol[4];
        for (int e = 0; e < 4; ++e) ol[e] = f2bf(f[e] * sc * wf[e]);
        *(uint2*)&hb[(size_t)row * DMODEL + tid * 4] = *(uint2*)ol;
        return;
    }
    const float* in; us* out; int K, N, nt, kt;
    if (tb < 4096) {
        int w = tb >> 10, u = tb & 1023;
        in = (w == 0) ? wq : (w == 1) ? wk : (w == 2) ? wv : wo;
        out = (w < 3) ? (wqkvt + (size_t)w * 1024 * 1024) : wot;
        K = 1024; N = 1024; nt = (u & 31) * 32; kt = (u >> 5) * 32;
    } else if (tb < 8192) {
        int u = tb - 4096;
        in = w1; out = w1t; K = 1024; N = 4096; nt = (u & 127) * 32; kt = (u >> 7) * 32;
    } else {
        int u = tb - 8192;
        in = w2; out = w2t; K = 4096; N = 1024; nt = (u & 31) * 32; kt = (u >> 5) * 32;
    }
    for (int i = 0; i < 4; ++i)
        tile[ty + 8 * i][tx] = f2bf(in[(size_t)(kt + ty + 8 * i) * N + nt + tx]);
    __syncthreads();
    for (int i = 0; i < 4; ++i)
        out[(size_t)(nt + ty + 8 * i) * K + kt + tx] = tile[tx][ty + 8 * i];
}

// ---------------- bf16 transpose: V (strided rows) -> Vt [B*D][T], key-permuted ---------
// Within each 64-key block, key k is stored at col sigma(k) = ((k&15)<<2)|((k&63)>>4).
// Matches the packed P storage in attn (storage col c holds key pi(c)=(c&3)*16+(c>>2);
// pi = sigma^-1), so the PV contraction sees identical key order on both operands.
__global__ void vtrans_k(const us* __restrict__ in, us* __restrict__ out, int istride) {
    __shared__ us tile[32][33];
    int b = blockIdx.z;
    int ct = blockIdx.x * 32;   // D tile
    int rt = blockIdx.y * 32;   // T tile
    int tx = threadIdx.x, ty = threadIdx.y; // (32,8)
    for (int i = 0; i < 4; ++i)
        tile[ty + 8 * i][tx] = in[((size_t)b * TSEQ + rt + ty + 8 * i) * istride + ct + tx];
    __syncthreads();
    int tt = rt + tx;
    int ts = (tt & ~63) | ((tt & 15) << 2) | ((tt & 63) >> 4);
    for (int i = 0; i < 4; ++i)
        out[((size_t)b * DMODEL + ct + ty + 8 * i) * TSEQ + ts] = tile[tx][ty + 8 * i];
}

// ---------------- Residual + RMSNorm: out = rmsnorm(a + b [+ b2]) * w ----------------
// NOTE: out may alias a (row-local) -> no __restrict__.
__global__ void resnorm_k(const us* a, const us* b,
                          const us* b2,
                          const float* w,
                          void* outp, int out_f32) {
    int row = blockIdx.x, t = threadIdx.x;
    us al[4], bl[4], cl[4];
    *(uint2*)al = *(const uint2*)&a[(size_t)row * DMODEL + t * 4];
    *(uint2*)bl = *(const uint2*)&b[(size_t)row * DMODEL + t * 4];
    if (b2) *(uint2*)cl = *(const uint2*)&b2[(size_t)row * DMODEL + t * 4];
    float f[4];
    float ss = 0.f;
    for (int e = 0; e < 4; ++e) {
        f[e] = bf2f(al[e]) + bf2f(bl[e]);
        if (b2) f[e] += bf2f(cl[e]);
        ss += f[e] * f[e];
    }
    for (int m = 1; m < 64; m <<= 1) ss += __shfl_xor(ss, m);
    __shared__ float red[4];
    if ((t & 63) == 0) red[t >> 6] = ss;
    __syncthreads();
    float tot = red[0] + red[1] + red[2] + red[3];
    float sc = rsqrtf(tot * (1.f / DMODEL) + 1e-6f);
    float4 wv = *(const float4*)&w[t * 4];
    float wf[4] = {wv.x, wv.y, wv.z, wv.w};
    if (out_f32) {
        float4 ov;
        ov.x = f[0] * sc * wf[0]; ov.y = f[1] * sc * wf[1];
        ov.z = f[2] * sc * wf[2]; ov.w = f[3] * sc * wf[3];
        *(float4*)&((float*)outp)[(size_t)row * DMODEL + t * 4] = ov;
    } else {
        us ol[4];
        for (int e = 0; e < 4; ++e) ol[e] = f2bf(f[e] * sc * wf[e]);
        *(uint2*)&((us*)outp)[(size_t)row * DMODEL + t * 4] = *(uint2*)ol;
    }
}

// ---------------- Residual + RMSNorm over 4 split-K partials (f32 out) ----------------
__global__ void resnorm4_k(const us* __restrict__ a, const us* __restrict__ p,
                           size_t pstride, const float* __restrict__ w,
                           float* __restrict__ out) {
    int row = blockIdx.x, t = threadIdx.x;
    size_t off = (size_t)row * DMODEL + t * 4;
    us al[4], pl[4][4];
    *(uint2*)al = *(const uint2*)&a[off];
#pragma unroll
    for (int z = 0; z < 4; ++z)
        *(uint2*)pl[z] = *(const uint2*)&p[off + z * pstride];
    float f[4];
    float ss = 0.f;
#pragma unroll
    for (int e = 0; e < 4; ++e) {
        f[e] = bf2f(al[e]) + bf2f(pl[0][e]) + bf2f(pl[1][e]) + bf2f(pl[2][e]) + bf2f(pl[3][e]);
        ss += f[e] * f[e];
    }
    for (int m = 1; m < 64; m <<= 1) ss += __shfl_xor(ss, m);
    __shared__ float red[4];
    if ((t & 63) == 0) red[t >> 6] = ss;
    __syncthreads();
    float tot = red[0] + red[1] + red[2] + red[3];
    float sc = rsqrtf(tot * (1.f / DMODEL) + 1e-6f);
    float4 wv = *(const float4*)&w[t * 4];
    float4 ov;
    ov.x = f[0] * sc * wv.x; ov.y = f[1] * sc * wv.y;
    ov.z = f[2] * sc * wv.z; ov.w = f[3] * sc * wv.w;
    *(float4*)&out[off] = ov;
}

// ---------------- legacy 128-tile 2-phase GEMM (kept for O-proj: short K, small) -------
template<int BN, int GX, bool SWZ>
__global__ __launch_bounds__(256, (BN == 256) ? 2 : 4)
void gemm_dbuf_k(const us* __restrict__ A,
                 const us* __restrict__ Bt,
                 us* __restrict__ C,
                 int M, int N, int K, int do_silu,
                 int Ks, size_t cstride) {
    constexpr int MI = 4, NI = BN / 32;
    constexpr int BDMA = BN / 64;
    __shared__ __align__(16) us As[2][128 * 32];
    __shared__ __align__(16) us Bs[2][BN * 32];
    int t = threadIdx.x;
    int n0 = blockIdx.x;
    int bx, by, z;
    if (SWZ) {
        int c = n0 & 7, bb = n0 >> 3;
        bx = bb % GX;
        int g = bb / GX;
        int yz = c + 8 * g;
        by = yz & 31; z = yz >> 5;
    } else {
        bx = n0 % GX;
        int bb = n0 / GX;
        by = bb & 31; z = bb >> 5;
    }
    int bm = by * 128, bn = bx * BN;
    int lane = t & 63, wave = t >> 6;
    int wm = (wave & 1) * 64, wn = (wave >> 1) * (BN / 2);
    int lr = lane & 15, lq = lane >> 4;

    int sr = lane >> 2;
    int sc = (((lane & 3) ^ ((lane >> 3) & 3)) * 8);
    const us* gA = A + (size_t)(bm + wave * 32 + sr) * K + sc + (size_t)z * Ks;
    const us* gB = Bt + (size_t)(bn + wave * (BN / 4) + sr) * K + sc + (size_t)z * Ks;
    const int aoff = (wave * 32) * 32;
    const int boff = (wave * (BN / 4)) * 32;
    C += (size_t)z * cstride;

    floatx4 acc[MI][NI];
#pragma unroll
    for (int mi = 0; mi < MI; ++mi)
#pragma unroll
        for (int ni = 0; ni < NI; ++ni)
            acc[mi][ni] = (floatx4){0.f, 0.f, 0.f, 0.f};

#pragma unroll
    for (int i = 0; i < 2; ++i)
        gld_lds16(gA + (size_t)(16 * i) * K, &As[0][aoff + i * 16 * 32]);
#pragma unroll
    for (int i = 0; i < BDMA; ++i)
        gld_lds16(gB + (size_t)(16 * i) * K, &Bs[0][boff + i * 16 * 32]);

    int aslot = ((lq ^ ((lr >> 1) & 3)) << 3);

    int nk = Ks >> 5;
    for (int kk = 0; kk < nk; ++kk) {
        __syncthreads();
        int cur = kk & 1, nxt = cur ^ 1;
        if (kk + 1 < nk) {
            size_t off = (size_t)(kk + 1) * 32;
#pragma unroll
            for (int i = 0; i < 2; ++i)
                gld_lds16(gA + (size_t)(16 * i) * K + off, &As[nxt][aoff + i * 16 * 32]);
#pragma unroll
            for (int i = 0; i < BDMA; ++i)
                gld_lds16(gB + (size_t)(16 * i) * K + off, &Bs[nxt][boff + i * 16 * 32]);
        }
        short8 a[MI], b[NI];
#pragma unroll
        for (int mi = 0; mi < MI; ++mi)
            a[mi] = *(const short8*)&As[cur][(wm + mi * 16 + lr) * 32 + aslot];
#pragma unroll
        for (int ni = 0; ni < NI; ++ni)
            b[ni] = *(const short8*)&Bs[cur][(wn + ni * 16 + lr) * 32 + aslot];
#pragma unroll
        for (int mi = 0; mi < MI; ++mi)
#pragma unroll
            for (int ni = 0; ni < NI; ++ni)
                acc[mi][ni] = __builtin_amdgcn_mfma_f32_16x16x32_bf16(a[mi], b[ni], acc[mi][ni], 0, 0, 0);
    }

#pragma unroll
    for (int mi = 0; mi < MI; ++mi)
#pragma unroll
        for (int ni = 0; ni < NI; ++ni)
#pragma unroll
            for (int r = 0; r < 4; ++r) {
                int m = bm + wm + mi * 16 + lq * 4 + r;
                int nn = bn + wn + ni * 16 + lr;
                float v = acc[mi][ni][r];
                if (do_silu) v = v / (1.f + __expf(-v));
                C[(size_t)m * N + nn] = f2bf(v);
            }
}

// ================= R20: 256x256 GEMM, 1 barrier per K-tile, reads-under-MFMA =============
// Evidence: R17(8ph)/R18(4ph)/R19(lean) all ~46-49us, MfmaUtil 28% -> the double-barrier
// phase structure serializes LDS-reads with MFMA every phase. R20: per K-tile, issue all
// B + first-half A reads up front, stage next tile immediately, then 4 MFMA quadrant
// bursts with trailing A-reads interleaved (compiler inserts counted lgkmcnt). ONE
// barrier per K-tile (16 vs 64); VM0 at tile end waits on ~2000-cy-old loads (cheap).
// Safety: every body ends VM0 (own staging landed) then BAR (all waves' reads of the
// overwritten buffer completed before their q3 MFMAs, hence before BAR).

#define BAR8 __builtin_amdgcn_s_barrier()
#define SB0  __builtin_amdgcn_sched_barrier(0)
#define VM0 do { asm volatile("s_waitcnt vmcnt(0)" ::: "memory"); } while (0)

template<int GX>
__global__ __launch_bounds__(512, 2)
void gemm8p_k(const us* __restrict__ A, const us* __restrict__ Bt, us* __restrict__ C,
              int N, int K, int Ks, int do_silu, size_t cstride) {
    __shared__ __align__(16) us Alds[2 * 2 * 128 * 64];   // 64 KiB ([2 dbuf][2 half][128][64])
    __shared__ __align__(16) us Blds[2 * 2 * 128 * 64];   // 64 KiB
    int t = threadIdx.x, lane = t & 63, wave = t >> 6;
    int n0 = blockIdx.x;
    int by = n0 & 15, rest = n0 >> 4;       // M=4096 fixed -> 16 row-blocks
    int bx = rest % GX, z = rest / GX;
    int bm = by * 256, bn = bx * 256;
    int lr = lane & 15, lq = (lane >> 4) & 3;
    int wm2 = wave >> 2, wn2 = wave & 3;

    // staging induction pointers (pre-swizzled chunk: LDS[row][c] = G[row][c ^ (row&7)])
    const size_t r8 = (size_t)8 * K;        // +8 rows
    const us* ga0 = A + (size_t)(bm + wave * 16 + (lane >> 3)) * K
                      + ((lane & 7) ^ (lane >> 3)) * 8 + (size_t)z * Ks;
    const us* ga1 = ga0 + (size_t)128 * K;  // h1 half
    const us* gb0 = Bt + (size_t)(bn + wave * 16 + (lane >> 3)) * K
                       + ((lane & 7) ^ (lane >> 3)) * 8 + (size_t)z * Ks;
    const us* gb1 = gb0 + (size_t)128 * K;
    const int sd = wave * 1024;             // wave's 16 rows x 64 within a half
    C += (size_t)z * cstride;

    // LDS read bases: slot = chunk ^ (row&7); ksub0 -> sw0, ksub1 -> sw1
    const int sw0 = ((lq ^ (lr & 7)) * 8);
    const int sw1 = (((4 + lq) ^ (lr & 7)) * 8);
    const us* pa00 = &Alds[wm2 * 8192 + lr * 64 + sw0];
    const us* pa01 = &Alds[wm2 * 8192 + lr * 64 + sw1];
    const us* pa10 = pa00 + 16384;
    const us* pa11 = pa01 + 16384;
    const int bo = (wn2 >> 1) * 8192 + (wn2 & 1) * 4096 + lr * 64;
    const us* pb00 = &Blds[bo + sw0];
    const us* pb01 = &Blds[bo + sw1];
    const us* pb10 = pb00 + 16384;
    const us* pb11 = pb01 + 16384;
    // LDS stage dests (wave-uniform)
    us* dA0h0 = &Alds[sd];          us* dA0h1 = &Alds[8192 + sd];
    us* dA1h0 = &Alds[16384 + sd];  us* dA1h1 = &Alds[16384 + 8192 + sd];
    us* dB0h0 = &Blds[sd];          us* dB0h1 = &Blds[8192 + sd];
    us* dB1h0 = &Blds[16384 + sd];  us* dB1h1 = &Blds[16384 + 8192 + sd];

#define STG_A2(d) do { \
    gld_lds16(ga0,      dA##d##h0); gld_lds16(ga0 + r8, dA##d##h0 + 512); \
    gld_lds16(ga1,      dA##d##h1); gld_lds16(ga1 + r8, dA##d##h1 + 512); \
    ga0 += 64; ga1 += 64; } while (0)
#define STG_B2(d) do { \
    gld_lds16(gb0,      dB##d##h0); gld_lds16(gb0 + r8, dB##d##h0 + 512); \
    gld_lds16(gb1,      dB##d##h1); gld_lds16(gb1 + r8, dB##d##h1 + 512); \
    gb0 += 64; gb1 += 64; } while (0)
#define RDA(sl, mf, D) do { \
    aF[sl][0] = *(const short8*)(pa##D##0 + (mf) * 1024); \
    aF[sl][1] = *(const short8*)(pa##D##1 + (mf) * 1024); } while (0)
#define RDB(nf, D) do { \
    bF[nf][0] = *(const short8*)(pb##D##0 + (nf) * 1024); \
    bF[nf][1] = *(const short8*)(pb##D##1 + (nf) * 1024); } while (0)
#define MMROW(mf, sl) do { \
    acc[mf][0] = __builtin_amdgcn_mfma_f32_16x16x32_bf16(aF[sl][0], bF[0][0], acc[mf][0], 0, 0, 0); \
    acc[mf][1] = __builtin_amdgcn_mfma_f32_16x16x32_bf16(aF[sl][0], bF[1][0], acc[mf][1], 0, 0, 0); \
    acc[mf][2] = __builtin_amdgcn_mfma_f32_16x16x32_bf16(aF[sl][0], bF[2][0], acc[mf][2], 0, 0, 0); \
    acc[mf][3] = __builtin_amdgcn_mfma_f32_16x16x32_bf16(aF[sl][0], bF[3][0], acc[mf][3], 0, 0, 0); \
    acc[mf][0] = __builtin_amdgcn_mfma_f32_16x16x32_bf16(aF[sl][1], bF[0][1], acc[mf][0], 0, 0, 0); \
    acc[mf][1] = __builtin_amdgcn_mfma_f32_16x16x32_bf16(aF[sl][1], bF[1][1], acc[mf][1], 0, 0, 0); \
    acc[mf][2] = __builtin_amdgcn_mfma_f32_16x16x32_bf16(aF[sl][1], bF[2][1], acc[mf][2], 0, 0, 0); \
    acc[mf][3] = __builtin_amdgcn_mfma_f32_16x16x32_bf16(aF[sl][1], bF[3][1], acc[mf][3], 0, 0, 0); } while (0)
#define PRIO1 __builtin_amdgcn_s_setprio(1)
#define PRIO0 __builtin_amdgcn_s_setprio(0)

// K-tile body reading buf D, staging next tile into buf E (= D^1):
#define TILE_S(D, E) do { \
    BAR8; \
    RDB(0, D); RDB(1, D); RDB(2, D); RDB(3, D); \
    RDA(0, 0, D); RDA(1, 1, D); RDA(2, 2, D); RDA(3, 3, D); \
    SB0; \
    STG_A2(E); STG_B2(E); \
    SB0; \
    PRIO1; MMROW(0, 0); MMROW(1, 1); PRIO0; \
    RDA(0, 4, D); RDA(1, 5, D); SB0; \
    PRIO1; MMROW(2, 2); MMROW(3, 3); PRIO0; \
    RDA(2, 6, D); RDA(3, 7, D); SB0; \
    PRIO1; MMROW(4, 0); MMROW(5, 1); PRIO0; \
    PRIO1; MMROW(6, 2); MMROW(7, 3); PRIO0; \
    VM0; } while (0)
#define TILE_N(D) do { \
    BAR8; \
    RDB(0, D); RDB(1, D); RDB(2, D); RDB(3, D); \
    RDA(0, 0, D); RDA(1, 1, D); RDA(2, 2, D); RDA(3, 3, D); \
    SB0; \
    PRIO1; MMROW(0, 0); MMROW(1, 1); PRIO0; \
    RDA(0, 4, D); RDA(1, 5, D); SB0; \
    PRIO1; MMROW(2, 2); MMROW(3, 3); PRIO0; \
    RDA(2, 6, D); RDA(3, 7, D); SB0; \
    PRIO1; MMROW(4, 0); MMROW(5, 1); PRIO0; \
    PRIO1; MMROW(6, 2); MMROW(7, 3); PRIO0; } while (0)

    floatx4 acc[8][4];
#pragma unroll
    for (int mf = 0; mf < 8; ++mf)
#pragma unroll
        for (int nf = 0; nf < 4; ++nf)
            acc[mf][nf] = (floatx4){0.f, 0.f, 0.f, 0.f};

    short8 aF[4][2], bF[4][2];

    // prologue: stage tile0 -> buf0; single exposed drain (once per kernel)
    STG_B2(0); STG_A2(0);
    VM0;

    const int NP = Ks >> 7;                 // pairs of K-tiles; Ks=1024 -> 8
    for (int i = 0; i < NP - 1; ++i) {
        TILE_S(0, 1);                       // tile 2i   (buf0), stages 2i+1 -> buf1
        TILE_S(1, 0);                       // tile 2i+1 (buf1), stages 2i+2 -> buf0
    }
    TILE_S(0, 1);                           // tile 2NP-2, stages last tile -> buf1
    TILE_N(1);                              // last tile, no stage

    // epilogue: C/D layout col = lane&15, row = (lane>>4)*4 + r
    int cm = bm + wm2 * 128, cn = bn + wn2 * 64;
#pragma unroll
    for (int mf = 0; mf < 8; ++mf)
#pragma unroll
        for (int nf = 0; nf < 4; ++nf)
#pragma unroll
            for (int r = 0; r < 4; ++r) {
                int m = cm + mf * 16 + lq * 4 + r;
                int nn = cn + nf * 16 + lr;
                float v = acc[mf][nf][r];
                if (do_silu) v = v / (1.f + __expf(-v));
                C[(size_t)m * N + nn] = f2bf(v);
            }
#undef STG_A2
#undef STG_B2
#undef RDA
#undef RDB
#undef MMROW
#undef PRIO1
#undef PRIO0
#undef TILE_S
#undef TILE_N
}

// ================= Flash attention: 512-thread blocks, 2 q-tiles sharing one K/V pass ======
// R17: P materialized via truncating bit-pack + ds_write_b64 (short4v, same TBAA class as
// the short8 reload) + explicit lgkmcnt(0)+sched_barrier fence before the PV reads.
// P storage col c holds key pi(c)=(c&3)*16+(c>>2); V is pre-permuted by sigma=pi^-1
// in vtrans_k so PV k-slots line up.
#define PSTR 72

template<bool DIAG>
__device__ __forceinline__ void flash_tile_nm(
    const short8& qf0, const short8& qf1,
    floatx4* oa, float* lrw,
    const us* Ks, const us* Vts, us* Ps, const short8& ones,
    int lr, int lq, int sub)
{
    floatx4 s[4];
#pragma unroll
    for (int n = 0; n < 4; ++n) {
        int R = n * 16 + lr;
        short8 kf0 = *(const short8*)&Ks[R * 64 + ((lq ^ (R & 7)) << 3)];
        short8 kf1 = *(const short8*)&Ks[R * 64 + (((lq + 4) ^ (R & 7)) << 3)];
        floatx4 z = (floatx4){0.f, 0.f, 0.f, 0.f};
        z = __builtin_amdgcn_mfma_f32_16x16x32_bf16(qf0, kf0, z, 0, 0, 0);
        s[n] = __builtin_amdgcn_mfma_f32_16x16x32_bf16(qf1, kf1, z, 0, 0, 0);
    }
    if (DIAG) {
#pragma unroll
        for (int n = 0; n < 4; ++n)
#pragma unroll
            for (int r = 0; r < 4; ++r)
                if ((n * 16 + lr) > (sub * 16 + lq * 4 + r)) s[n][r] = -1e30f;  // exp2 -> 0
    }
    // packed P write: keys {n*16+lr} -> storage cols lr*4+n (pi-permuted layout)
#pragma unroll
    for (int r = 0; r < 4; ++r) {
        union { unsigned int u[2]; short4v v; } pk;
        pk.u[0] = pk_trunc(__builtin_amdgcn_exp2f(s[0][r]), __builtin_amdgcn_exp2f(s[1][r]));
        pk.u[1] = pk_trunc(__builtin_amdgcn_exp2f(s[2][r]), __builtin_amdgcn_exp2f(s[3][r]));
        *(short4v*)&Ps[(lq * 4 + r) * PSTR + lr * 4] = pk.v;
    }
    // ensure the 4 ds_write_b64 above complete before the same wave's ds_reads below
    asm volatile("s_waitcnt lgkmcnt(0)" ::: "memory");
    __builtin_amdgcn_sched_barrier(0);

    floatx4 zs = (floatx4){0.f, 0.f, 0.f, 0.f};
    __builtin_amdgcn_s_setprio(1);
#pragma unroll
    for (int kx = 0; kx < 2; ++kx) {
        short8 pf = *(const short8*)&Ps[lr * PSTR + kx * 32 + lq * 8];
        zs = __builtin_amdgcn_mfma_f32_16x16x32_bf16(pf, ones, zs, 0, 0, 0);
#pragma unroll
        for (int nd = 0; nd < 4; ++nd) {
            int R = nd * 16 + lr;
            short8 vf = *(const short8*)&Vts[R * 64 + ((((kx << 2) | lq) ^ (R & 7)) << 3)];
            oa[nd] = __builtin_amdgcn_mfma_f32_16x16x32_bf16(pf, vf, oa[nd], 0, 0, 0);
        }
    }
    __builtin_amdgcn_s_setprio(0);
#pragma unroll
    for (int r = 0; r < 4; ++r) lrw[r] += zs[r];
}

__global__ __launch_bounds__(512, 6) void attn_k(const us* __restrict__ q,
                                                 const us* __restrict__ kg,
                                                 const us* __restrict__ vt,
                                                 us* __restrict__ o,
                                                 us* __restrict__ Po,
                                                 float* __restrict__ Pl) {
    __shared__ __align__(16) us Ks[2][64 * 64];
    __shared__ __align__(16) us Vts[2][64 * 64];
    __shared__ __align__(16) us Ps[8 * 16 * PSTR];
    int j = blockIdx.x;
    int part = (j >= 16);
    int P = part ? (j - 8) : j;
    int qtA = 2 * P, qtB = 2 * P + 1;
    int k0 = part ? 16 : 0;
    int k1 = part ? qtB : (qtB < 15 ? qtB : 15);
    bool fin = (!part) && (P < 8);
    int bh = blockIdx.y;
    int b = bh >> 4, h = bh & 15;
    size_t base = (size_t)b * TSEQ;
    const us* vth = vt + ((size_t)b * DMODEL + h * 64) * TSEQ;
    int t = threadIdx.x, lane = t & 63, wave = t >> 6;   // wave 0..7
    int sub = wave & 3, grp = wave >> 2;                 // strip index, q-tile group
    int myqt = grp ? qtB : qtA;
    int lr = lane & 15, lq = lane >> 4;

    const float SC = 0.18033688011112042f;  // (1/8)*log2(e)
    int qrow = myqt * 64 + sub * 16 + lr;
    short8 qf0 = *(const short8*)&q[(base + qrow) * QKVS + h * 64 + lq * 8];
    short8 qf1 = *(const short8*)&q[(base + qrow) * QKVS + h * 64 + 32 + lq * 8];
#pragma unroll
    for (int e = 0; e < 8; ++e) {
        qf0[e] = (short)f2bf(bf2f((us)qf0[e]) * SC);
        qf1[e] = (short)f2bf(bf2f((us)qf1[e]) * SC);
    }
    short8 ones;
#pragma unroll
    for (int e = 0; e < 8; ++e) ones[e] = (short)0x3F80;  // bf16 1.0

    us* Psw = &Ps[wave * 16 * PSTR];

    floatx4 oa[4];
    float lrw[4] = {0.f, 0.f, 0.f, 0.f};
#pragma unroll
    for (int i = 0; i < 4; ++i) oa[i] = (floatx4){0.f, 0.f, 0.f, 0.f};

    int rsub = lane >> 3;
    int cda = ((lane & 7) ^ rsub) * 8;
    const us* gK = kg + (base + wave * 8 + rsub) * QKVS + h * 64 + cda;
    const us* gV = vth + (size_t)(wave * 8 + rsub) * TSEQ + cda;

    gld_lds16(gK + (size_t)(k0 * 64) * QKVS, &Ks[0][(wave * 8) * 64]);
    gld_lds16(gV + k0 * 64, &Vts[0][(wave * 8) * 64]);

    for (int kt = k0; kt <= k1; ++kt) {
        __syncthreads();
        int cur = (kt - k0) & 1, nxt = cur ^ 1;
        if (kt < k1) {
            gld_lds16(gK + (size_t)((kt + 1) * 64) * QKVS, &Ks[nxt][(wave * 8) * 64]);
            gld_lds16(gV + (kt + 1) * 64, &Vts[nxt][(wave * 8) * 64]);
        }
        if (kt <= myqt) {
            if (kt == myqt)
                flash_tile_nm<true>(qf0, qf1, oa, lrw, Ks[cur], Vts[cur], Psw, ones, lr, lq, sub);
            else
                flash_tile_nm<false>(qf0, qf1, oa, lrw, Ks[cur], Vts[cur], Psw, ones, lr, lq, sub);
        }
    }

    if (fin) {
#pragma unroll
        for (int nd = 0; nd < 4; ++nd)
#pragma unroll
            for (int r = 0; r < 4; ++r) {
                int tok = myqt * 64 + sub * 16 + lq * 4 + r;
                o[(base + tok) * DMODEL + h * 64 + nd * 16 + lr] = f2bf(oa[nd][r] / lrw[r]);
            }
    } else {
#pragma unroll
        for (int nd = 0; nd < 4; ++nd)
#pragma unroll
            for (int r = 0; r < 4; ++r) {
                int tok = myqt * 64 + sub * 16 + lq * 4 + r;
                size_t pb = ((size_t)(part * BATCH + b) * 1024 + (tok - 1024)) * 1024;
                Po[pb + h * 64 + nd * 16 + lr] = f2bf(oa[nd][r]);
            }
        if (lr == 0) {
#pragma unroll
            for (int r = 0; r < 4; ++r) {
                int tok = myqt * 64 + sub * 16 + lq * 4 + r;
                Pl[((part * BATCH + b) * NHEADS + h) * TSEQ + tok] = lrw[r];
            }
        }
    }
}

__global__ void merge_k(const us* __restrict__ Po, const float* __restrict__ Pl,
                        us* __restrict__ ab) {
    int row = blockIdx.x;            // 0..2047
    int b = row >> 10, tloc = row & 1023;
    int t = 1024 + tloc;
    int t4 = threadIdx.x * 4;
    int h = t4 >> 6;
    float l0 = Pl[((0 * BATCH + b) * NHEADS + h) * TSEQ + t];
    float l1 = Pl[((1 * BATCH + b) * NHEADS + h) * TSEQ + t];
    float inv = 1.f / (l0 + l1);
    size_t o0 = ((size_t)(0 * BATCH + b) * 1024 + tloc) * 1024 + t4;
    size_t o1 = ((size_t)(1 * BATCH + b) * 1024 + tloc) * 1024 + t4;
    us p0[4], p1[4], ol[4];
    *(uint2*)p0 = *(const uint2*)&Po[o0];
    *(uint2*)p1 = *(const uint2*)&Po[o1];
    for (int e = 0; e < 4; ++e)
        ol[e] = f2bf((bf2f(p0[e]) + bf2f(p1[e])) * inv);
    *(uint2*)&ab[((size_t)b * TSEQ + t) * DMODEL + t4] = *(uint2*)ol;
}

// ---------------- launch ----------------
extern "C" void kernel_launch(void* const* d_in, const int* in_sizes, int n_in,
                              void* d_out, int out_size, void* d_ws, size_t ws_size,
                              hipStream_t stream) {
    const float* x      = (const float*)d_in[0];
    const float* w_pre  = (const float*)d_in[1];
    const float* wq     = (const float*)d_in[2];
    const float* wk     = (const float*)d_in[3];
    const float* wv     = (const float*)d_in[4];
    const float* wo     = (const float*)d_in[5];
    const float* w_attn = (const float*)d_in[6];
    const float* w1     = (const float*)d_in[7];
    const float* w2     = (const float*)d_in[8];
    const float* w_ffn  = (const float*)d_in[9];

    char* ws = (char*)d_ws;
    const size_t MB = 1024 * 1024;
    us* hb    = (us*)(ws + 0);
    us* qkvb  = (us*)(ws + 8 * MB);
    us* ab    = (us*)(ws + 32 * MB);
    us* vtb   = (us*)(ws + 40 * MB);
    us* ob0   = (us*)(ws + 40 * MB);
    us* ob1   = (us*)(ws + 48 * MB);
    us* Pob   = (us*)(ws + 48 * MB);
    us* yb    = (us*)(ws + 0);        // in-place over hb (row-local safe)
    us* wqkvt = (us*)(ws + 56 * MB);  // 6 MB
    us* wot   = (us*)(ws + 62 * MB);  // 2 MB
    us* w1t   = (us*)(ws + 64 * MB);  // 8 MB
    us* w2t   = (us*)(ws + 72 * MB);  // 8 MB
    float* Pl = (float*)(ws + 80 * MB); // 1 MB
    us* midb  = (us*)(ws + 8 * MB);   // 32 MB FFN mid (qkvb+ab dead)
    us* fb0   = (us*)(ws + 40 * MB);  // FFN2 split-K=4 partials, 8 MB stride
    const size_t FB_STR = (8 * MB) / 2;

    dim3 tb(32, 8);
    // 6 transposes + pre-norm in one launch (12288 tiles + 4096 rows)
    prologue_k<<<dim3(16384), tb, 0, stream>>>(
        wq, wk, wv, wo, w1, w2, x, w_pre, wqkvt, wot, w1t, w2t, hb);

    // fused QKV: R20 1-barrier/K-tile 256x256, 16x12 = 192 blocks
    gemm8p_k<12><<<dim3(192), 512, 0, stream>>>(
        hb, wqkvt, qkvb, QKVS, DMODEL, DMODEL, 0, 0);

    vtrans_k<<<dim3(DMODEL / 32, TSEQ / 32, BATCH), tb, 0, stream>>>(qkvb + 2048, vtb, QKVS);

    attn_k<<<dim3(24, BATCH * NHEADS), 512, 0, stream>>>(qkvb, qkvb + 1024, vtb, ab, Pob, Pl);
    merge_k<<<dim3(BATCH * 1024), 256, 0, stream>>>(Pob, Pl, ab);

    // O-proj: legacy 2-phase, GX=8, split-K=2 -> 512 blocks (short K; small op)
    gemm_dbuf_k<128, 8, true><<<dim3(512), 256, 0, stream>>>(
        ab, wot, ob0, BT, DMODEL, DMODEL, 0, DMODEL / 2, (size_t)BT * DMODEL);
    resnorm_k<<<BT, 256, 0, stream>>>(hb, ob0, ob1, w_attn, yb, 0);

    // FFN1: R20 256x256, 16x16 = 256 blocks, fused silu
    gemm8p_k<16><<<dim3(256), 512, 0, stream>>>(
        yb, w1t, midb, FFDIM, DMODEL, DMODEL, 1, 0);
    // FFN2: R20 256x256, split-K=4 -> 16x4x4 = 256 blocks, Ks=1024
    gemm8p_k<4><<<dim3(256), 512, 0, stream>>>(
        midb, w2t, fb0, DMODEL, FFDIM, FFDIM / 4, 0, FB_STR);
    resnorm4_k<<<BT, 256, 0, stream>>>(yb, fb0, FB_STR, w_ffn, (float*)d_out);
}